// Round 5
// baseline (503.701 us; speedup 1.0000x reference)
//
#include <hip/hip_runtime.h>

#define NN 100000
#define NE 1600000
#define INF 4
#define H 128
#define RR 20
#define OUTF 2
#define NB 782            // buckets of 128 nodes: ceil(100000/128)
#define NB8 (NB * 8)      // per-(bucket, xcd-proxy) counters

typedef unsigned int uint32;

// round-to-nearest-even bf16 pack: x -> low 16, y -> high 16
__device__ inline uint32 pack_bf16(float x, float y) {
    uint32 ux = __float_as_uint(x);
    uint32 uy = __float_as_uint(y);
    ux = (ux + 0x7fffu + ((ux >> 16) & 1u)) >> 16;
    uy = (uy + 0x7fffu + ((uy >> 16) & 1u)) & 0xffff0000u;
    return ux | uy;
}

// ---------------- init ----------------
__global__ void k_init_small(float* __restrict__ pooled, int* __restrict__ in_size) {
    int t = threadIdx.x;
    if (t < H) pooled[t] = 0.f;
    if (t == H) *in_size = 0;
}

__global__ void k_init_nodes(const float* __restrict__ x, int* __restrict__ in_size) {
    int i = blockIdx.x * 256 + threadIdx.x;
    bool pred = false;
    if (i < NN) {
        float x0 = x[(size_t)i * INF + 0];
        float x1 = x[(size_t)i * INF + 1];
        pred = (x0 != 0.f) && (x1 != 0.f);
    }
    unsigned long long m = __ballot(pred);
    if ((threadIdx.x & 63) == 0) {
        int c = __popcll(m);
        if (c) atomicAdd(in_size, c);
    }
}

// ---------------- bucketed CSR construction ----------------
// count edges per (bucket, xcd-proxy). blockIdx&7 ~ XCD under round-robin
// dispatch; partition choice only affects write locality, never correctness.
__global__ void k_count(const int* __restrict__ dst, int* __restrict__ cnt) {
    int e = blockIdx.x * 256 + threadIdx.x;
    if (e < NE) atomicAdd(&cnt[(dst[e] >> 7) * 8 + (blockIdx.x & 7)], 1);
}

// exclusive scan of the 6256 counters (bucket-major) -> sub-segment bases.
__global__ void __launch_bounds__(1024) k_scanbkt(const int* __restrict__ cnt,
                                                  int* __restrict__ base,
                                                  int* __restrict__ cur) {
    __shared__ int sm[1024];
    int t = threadIdx.x;
    int carry = 0;
    for (int c = 0; c < 7; ++c) {
        int i = c * 1024 + t;
        int v = (i < NB8) ? cnt[i] : 0;
        sm[t] = v;
        __syncthreads();
        for (int off = 1; off < 1024; off <<= 1) {
            int u = (t >= off) ? sm[t - off] : 0;
            __syncthreads();
            sm[t] += u;
            __syncthreads();
        }
        if (i < NB8) {
            int excl = carry + sm[t] - v;
            base[i] = excl;
            cur[i] = excl;
        }
        carry += sm[1023];
        __syncthreads();
    }
    if (t == 0) base[NB8] = NE;
}

// scatter packed records (src<<7 | dst&127) into per-(bucket,xcd) sub-segments.
// Each sub-segment is appended by one XCD-proxy -> full-line writes.
__global__ void k_scatter(const int* __restrict__ src, const int* __restrict__ dst,
                          int* __restrict__ cur, uint32* __restrict__ data) {
    int e = blockIdx.x * 256 + threadIdx.x;
    if (e < NE) {
        int s = src[e], d = dst[e];
        int p = atomicAdd(&cur[(d >> 7) * 8 + (blockIdx.x & 7)], 1);
        data[p] = ((uint32)s << 7) | (uint32)(d & 127);
    }
}

// one block per bucket: histogram -> deg/dinv/csr_off + node-sorted csr_src.
// Bucket's record range is contiguous: [base[b*8], base[(b+1)*8]).
__global__ void __launch_bounds__(256) k_build(const uint32* __restrict__ data,
                                               const int* __restrict__ base,
                                               int* __restrict__ csr_off,
                                               int* __restrict__ csr_src,
                                               float* __restrict__ dinv) {
    __shared__ int hist[128], pfx[128], curs[128];
    int bkt = blockIdx.x;
    int t = threadIdx.x;
    int rbeg = base[bkt * 8];
    int rend = base[(bkt + 1) * 8];
    if (t < 128) hist[t] = 0;
    __syncthreads();
    for (int j = rbeg + t; j < rend; j += 256)
        atomicAdd(&hist[data[j] & 127], 1);
    __syncthreads();
    if (t < 128) pfx[t] = hist[t];
    __syncthreads();
    for (int off = 1; off < 128; off <<= 1) {
        int u = (t < 128 && t >= off) ? pfx[t - off] : 0;
        __syncthreads();
        if (t < 128) pfx[t] += u;
        __syncthreads();
    }
    int nodeCount = min(128, NN - bkt * 128);
    if (t < nodeCount) {
        int excl = rbeg + pfx[t] - hist[t];
        csr_off[bkt * 128 + t] = excl;
        curs[t] = excl;
        dinv[bkt * 128 + t] = rsqrtf((float)(hist[t] + 1));
    }
    if (bkt == NB - 1 && t == 0) csr_off[NN] = NE;
    __syncthreads();
    for (int j = rbeg + t; j < rend; j += 256) {
        uint32 r = data[j];
        int p = atomicAdd(&curs[r & 127], 1);
        csr_src[p] = (int)(r >> 7);
    }
}

// ---------------- layer 1: aggregate x (4 features) ----------------
__global__ void k_aggx(const float* __restrict__ x, const int* __restrict__ csr_off,
                       const int* __restrict__ csr_src, const float* __restrict__ dinv,
                       float* __restrict__ Ax) {
    int i = blockIdx.x * 256 + threadIdx.x;
    if (i >= NN) return;
    int b = csr_off[i], e = csr_off[i + 1];
    float a0 = 0.f, a1 = 0.f, a2 = 0.f, a3 = 0.f;
    for (int j = b; j < e; ++j) {
        int s = csr_src[j];
        float w = dinv[s];
        const float4 xv = *(const float4*)(x + (size_t)s * INF);
        a0 += xv.x * w; a1 += xv.y * w; a2 += xv.z * w; a3 += xv.w * w;
    }
    float di = dinv[i];
    const float4 xi = *(const float4*)(x + (size_t)i * INF);
    a0 = (a0 + xi.x * di) * di;
    a1 = (a1 + xi.y * di) * di;
    a2 = (a2 + xi.z * di) * di;
    a3 = (a3 + xi.w * di) * di;
    *(float4*)(Ax + (size_t)i * INF) = make_float4(a0, a1, a2, a3);
}

// Yp = pack_bf16( tanh(Ax @ W1 + b1) * dinv )   [N, 64] uint (2 bf16 feats/lane)
__global__ void k_mm1(const float* __restrict__ Ax, const float* __restrict__ W1,
                      const float* __restrict__ b1, const float* __restrict__ dinv,
                      uint32* __restrict__ Yp) {
    int tid = threadIdx.x;
    int wid = tid >> 6, lane = tid & 63;
    int node = blockIdx.x * 4 + wid;
    if (node >= NN) return;
    const float4 a = *(const float4*)(Ax + (size_t)node * INF);
    float di = dinv[node];
    int f0 = lane * 2;
    const float2 w0 = *(const float2*)(W1 + 0 * H + f0);
    const float2 w1 = *(const float2*)(W1 + 1 * H + f0);
    const float2 w2 = *(const float2*)(W1 + 2 * H + f0);
    const float2 w3 = *(const float2*)(W1 + 3 * H + f0);
    const float2 bb = *(const float2*)(b1 + f0);
    float acc0 = bb.x + a.x * w0.x + a.y * w1.x + a.z * w2.x + a.w * w3.x;
    float acc1 = bb.y + a.x * w0.y + a.y * w1.y + a.z * w2.y + a.w * w3.y;
    Yp[(size_t)node * 64 + lane] = pack_bf16(tanhf(acc0) * di, tanhf(acc1) * di);
}

// ---------------- layer 2 gather: Z = dinv[i] * (sum Yp[s] + Yp[i]) -------------
__global__ void k_aggy(const uint32* __restrict__ Yp, const int* __restrict__ csr_off,
                       const int* __restrict__ csr_src, const float* __restrict__ dinv,
                       float* __restrict__ Z) {
    int wid = threadIdx.x >> 6;
    int lane = threadIdx.x & 63;
    int i = blockIdx.x * 4 + wid;
    if (i >= NN) return;
    int b = csr_off[i], e = csr_off[i + 1];
    float a0 = 0.f, a1 = 0.f;
    int j = b;
    for (; j + 2 <= e; j += 2) {
        int s0 = csr_src[j];
        int s1 = csr_src[j + 1];
        uint32 v0 = Yp[(size_t)s0 * 64 + lane];
        uint32 v1 = Yp[(size_t)s1 * 64 + lane];
        a0 += __uint_as_float(v0 << 16);
        a1 += __uint_as_float(v0 & 0xffff0000u);
        a0 += __uint_as_float(v1 << 16);
        a1 += __uint_as_float(v1 & 0xffff0000u);
    }
    if (j < e) {
        uint32 v = Yp[(size_t)csr_src[j] * 64 + lane];
        a0 += __uint_as_float(v << 16);
        a1 += __uint_as_float(v & 0xffff0000u);
    }
    uint32 vi = Yp[(size_t)i * 64 + lane];
    a0 += __uint_as_float(vi << 16);
    a1 += __uint_as_float(vi & 0xffff0000u);
    float di = dinv[i];
    *(float2*)(Z + (size_t)i * H + lane * 2) = make_float2(a0 * di, a1 * di);
}

// ---------------- O = tanh(Z @ W2 + b2), fused mean-pool accumulation ------------
__global__ void __launch_bounds__(256) k_mm2pool(
    const float* __restrict__ Z, const float* __restrict__ W2,
    const float* __restrict__ b2, float* __restrict__ pooled) {
    __shared__ float w2s[H][64];   // [k][feat-in-half], 32 KB
    __shared__ float zt[H][64];    // [k][node^swz],     32 KB

    int tid = threadIdx.x;
    int fhalf = blockIdx.x & 1;

    #pragma unroll
    for (int rep = 0; rep < 8; ++rep) {
        int flat = rep * 256 + tid;
        int k = flat >> 4;
        int j4 = (flat & 15) * 4;
        float4 v = *(const float4*)(W2 + (size_t)k * H + fhalf * 64 + j4);
        *(float4*)(&w2s[k][j4]) = v;
    }

    int wid = tid >> 6, lane = tid & 63;
    int ng = lane & 15, fg = lane >> 4;
    int fbase = fhalf * 64 + wid * 16 + fg * 4;
    int fcol  = wid * 16 + fg * 4;

    float bias[4];
    #pragma unroll
    for (int b = 0; b < 4; ++b) bias[b] = b2[fbase + b];

    float pool[4] = {0.f, 0.f, 0.f, 0.f};

    const int ntiles = (NN + 63) >> 6;           // 1563
    for (int tile = blockIdx.x >> 1; tile < ntiles; tile += (int)(gridDim.x >> 1)) {
        __syncthreads();
        int nbase = tile << 6;
        #pragma unroll
        for (int rep = 0; rep < 8; ++rep) {
            int flat = rep * 256 + tid;
            int node = flat >> 5;
            int k4 = (flat & 31) * 4;
            int gi = nbase + node;
            float4 v = make_float4(0.f, 0.f, 0.f, 0.f);
            if (gi < NN) v = *(const float4*)(Z + (size_t)gi * H + k4);
            #pragma unroll
            for (int i = 0; i < 4; ++i) {
                int k = k4 + i;
                int col = node ^ (((k >> 2) & 15) << 2);
                zt[k][col] = (&v.x)[i];
            }
        }
        __syncthreads();

        float acc[4][4];
        #pragma unroll
        for (int a = 0; a < 4; ++a)
            #pragma unroll
            for (int b = 0; b < 4; ++b) acc[a][b] = bias[b];

        #pragma unroll 4
        for (int k = 0; k < H; ++k) {
            int zc = (ng * 4) ^ (((k >> 2) & 15) << 2);
            const float4 zv = *(const float4*)(&zt[k][zc]);
            const float4 wv = *(const float4*)(&w2s[k][fcol]);
            acc[0][0] += zv.x * wv.x; acc[0][1] += zv.x * wv.y; acc[0][2] += zv.x * wv.z; acc[0][3] += zv.x * wv.w;
            acc[1][0] += zv.y * wv.x; acc[1][1] += zv.y * wv.y; acc[1][2] += zv.y * wv.z; acc[1][3] += zv.y * wv.w;
            acc[2][0] += zv.z * wv.x; acc[2][1] += zv.z * wv.y; acc[2][2] += zv.z * wv.z; acc[2][3] += zv.z * wv.w;
            acc[3][0] += zv.w * wv.x; acc[3][1] += zv.w * wv.y; acc[3][2] += zv.w * wv.z; acc[3][3] += zv.w * wv.w;
        }

        #pragma unroll
        for (int a = 0; a < 4; ++a) {
            bool valid = (nbase + ng * 4 + a) < NN;
            #pragma unroll
            for (int b = 0; b < 4; ++b) {
                pool[b] += valid ? tanhf(acc[a][b]) : 0.f;
            }
        }
    }

    #pragma unroll
    for (int b = 0; b < 4; ++b) {
        float t = pool[b];
        t += __shfl_xor(t, 1, 64);
        t += __shfl_xor(t, 2, 64);
        t += __shfl_xor(t, 4, 64);
        t += __shfl_xor(t, 8, 64);
        if (ng == 0) atomicAdd(&pooled[fbase + b], t);
    }
}

// ---------------- final: vel = (pooled/N) @ Wfc + bfc, mask by in_size ----------
__global__ void k_final(const float* __restrict__ pooled, const float* __restrict__ Wfc,
                        const float* __restrict__ bfc, const int* __restrict__ in_size,
                        float* __restrict__ out) {
    int t = threadIdx.x;
    if (t >= RR * OUTF) return;
    const float invn = 1.0f / (float)NN;
    float a = bfc[t];
    for (int k = 0; k < H; ++k) a += (pooled[k] * invn) * Wfc[k * (RR * OUTF) + t];
    int r = t >> 1;
    out[t] = (r < *in_size) ? a : 0.f;
}

extern "C" void kernel_launch(void* const* d_in, const int* in_sizes, int n_in,
                              void* d_out, int out_size, void* d_ws, size_t ws_size,
                              hipStream_t stream) {
    const float* x   = (const float*)d_in[0];
    const int*   ei  = (const int*)d_in[1];     // [2, E]
    const float* W1  = (const float*)d_in[3];
    const float* b1  = (const float*)d_in[4];
    const float* W2  = (const float*)d_in[5];
    const float* b2  = (const float*)d_in[6];
    const float* Wfc = (const float*)d_in[7];
    const float* bfc = (const float*)d_in[8];
    float* out = (float*)d_out;

    const int* srcp = ei;
    const int* dstp = ei + NE;

    // workspace layout (512B aligned chunks)
    char* ws = (char*)d_ws;
    size_t off = 0;
    auto alloc = [&](size_t bytes) { void* p = ws + off; off += (bytes + 511) & ~(size_t)511; return p; };
    int*    bktcnt  = (int*)alloc((size_t)NB8 * 4);
    int*    bktbase = (int*)alloc(((size_t)NB8 + 1) * 4);
    int*    bktcur  = (int*)alloc((size_t)NB8 * 4);
    uint32* bktdata = (uint32*)alloc((size_t)NE * 4);
    float*  dinv    = (float*)alloc((size_t)NN * 4);
    int*    csr_off = (int*)alloc(((size_t)NN + 1) * 4);
    int*    csr_src = (int*)alloc((size_t)NE * 4);
    float*  Ax      = (float*)alloc((size_t)NN * INF * 4);
    uint32* Yp      = (uint32*)alloc((size_t)NN * 64 * 4);   // packed bf16, premult by dinv
    float*  Z       = (float*)alloc((size_t)NN * H * 4);
    float*  pooled  = (float*)alloc(H * 4);
    int*    in_size = (int*)alloc(64);
    (void)off; (void)ws_size; (void)in_sizes; (void)n_in; (void)out_size;

    const int nbN = (NN + 255) / 256;        // 391
    const int nbE = (NE + 255) / 256;        // 6250
    const int nbW = (NN + 3) / 4;            // 4 waves (nodes) per block

    hipMemsetAsync(bktcnt, 0, (size_t)NB8 * 4, stream);
    k_init_small<<<1, 256, 0, stream>>>(pooled, in_size);
    k_init_nodes<<<nbN, 256, 0, stream>>>(x, in_size);
    k_count<<<nbE, 256, 0, stream>>>(dstp, bktcnt);
    k_scanbkt<<<1, 1024, 0, stream>>>(bktcnt, bktbase, bktcur);
    k_scatter<<<nbE, 256, 0, stream>>>(srcp, dstp, bktcur, bktdata);
    k_build<<<NB, 256, 0, stream>>>(bktdata, bktbase, csr_off, csr_src, dinv);
    k_aggx<<<nbN, 256, 0, stream>>>(x, csr_off, csr_src, dinv, Ax);
    k_mm1<<<nbW, 256, 0, stream>>>(Ax, W1, b1, dinv, Yp);
    k_aggy<<<nbW, 256, 0, stream>>>(Yp, csr_off, csr_src, dinv, Z);
    k_mm2pool<<<512, 256, 0, stream>>>(Z, W2, b2, pooled);
    k_final<<<1, 64, 0, stream>>>(pooled, Wfc, bfc, in_size, out);
}

// Round 7
// 406.752 us; speedup vs baseline: 1.2383x; 1.2383x over previous
//
#include <hip/hip_runtime.h>

#define NN 100000
#define NE 1600000
#define INF 4
#define H 128
#define RR 20
#define OUTF 2
#define NB 782            // buckets of 128 nodes: ceil(100000/128)
#define CAP 4096          // record slots per bucket (mean 2048)
#define SUB 512           // per-(bucket, xcd-proxy) sub-segment (mean 256, +16 sigma)

typedef unsigned int uint32;

// round-to-nearest-even bf16 pack: x -> low 16, y -> high 16
__device__ inline uint32 pack_bf16(float x, float y) {
    uint32 ux = __float_as_uint(x);
    uint32 uy = __float_as_uint(y);
    ux = (ux + 0x7fffu + ((ux >> 16) & 1u)) >> 16;
    uy = (uy + 0x7fffu + ((uy >> 16) & 1u)) & 0xffff0000u;
    return ux | uy;
}

// ---------------- init ----------------
__global__ void k_init_small(float* __restrict__ pooled, int* __restrict__ in_size) {
    int t = threadIdx.x;
    if (t < H) pooled[t] = 0.f;
    if (t == H) *in_size = 0;
}

__global__ void k_init_nodes(const float* __restrict__ x, int* __restrict__ in_size) {
    int i = blockIdx.x * 256 + threadIdx.x;
    bool pred = false;
    if (i < NN) {
        float x0 = x[(size_t)i * INF + 0];
        float x1 = x[(size_t)i * INF + 1];
        pred = (x0 != 0.f) && (x1 != 0.f);
    }
    unsigned long long m = __ballot(pred);
    if ((threadIdx.x & 63) == 0) {
        int c = __popcll(m);
        if (c) atomicAdd(in_size, c);
    }
}

// ---------------- one-pass bucketed scatter ----------------
// Record (src<<7 | dst&127) appended to fixed-capacity sub-segment
// (bucket = dst>>7, proxy = blockIdx&7 ~ XCD under round-robin dispatch).
// Proxy choice affects only write locality, never correctness.
__global__ void k_scatter(const int* __restrict__ src, const int* __restrict__ dst,
                          int* __restrict__ cnt, uint32* __restrict__ data) {
    int e = blockIdx.x * 256 + threadIdx.x;
    if (e < NE) {
        int s = src[e], d = dst[e];
        int bkt = d >> 7, px = blockIdx.x & 7;
        int p = atomicAdd(&cnt[bkt * 8 + px], 1);
        if (p < SUB)   // cannot trigger (+16 sigma); guards OOB
            data[(size_t)bkt * CAP + px * SUB + p] = ((uint32)s << 7) | (uint32)(d & 127);
    }
}

// one block per bucket: histogram -> csr_off/csr_cnt/dinv + node-sorted csr_src.
__global__ void __launch_bounds__(256) k_build(const uint32* __restrict__ data,
                                               const int* __restrict__ cnt,
                                               int* __restrict__ csr_off,
                                               int* __restrict__ csr_cnt,
                                               int* __restrict__ csr_src,
                                               float* __restrict__ dinv) {
    __shared__ int hist[128], pfx[128], curs[128], scnt[8];
    int bkt = blockIdx.x;
    int t = threadIdx.x;
    if (t < 128) hist[t] = 0;
    if (t >= 128 && t < 136) scnt[t - 128] = min(cnt[bkt * 8 + (t - 128)], SUB);
    __syncthreads();
    for (int c = 0; c < 8; ++c) {
        int base = bkt * CAP + c * SUB, n = scnt[c];
        for (int j = t; j < n; j += 256)
            atomicAdd(&hist[data[base + j] & 127], 1);
    }
    __syncthreads();
    if (t < 128) pfx[t] = hist[t];
    __syncthreads();
    for (int off = 1; off < 128; off <<= 1) {
        int u = (t < 128 && t >= off) ? pfx[t - off] : 0;
        __syncthreads();
        if (t < 128) pfx[t] += u;
        __syncthreads();
    }
    int nodeCount = min(128, NN - bkt * 128);
    if (t < nodeCount) {
        int excl = bkt * CAP + pfx[t] - hist[t];
        csr_off[bkt * 128 + t] = excl;
        csr_cnt[bkt * 128 + t] = hist[t];
        curs[t] = excl;
        dinv[bkt * 128 + t] = rsqrtf((float)(hist[t] + 1));
    }
    __syncthreads();
    for (int c = 0; c < 8; ++c) {
        int base = bkt * CAP + c * SUB, n = scnt[c];
        for (int j = t; j < n; j += 256) {
            uint32 r = data[base + j];
            int p = atomicAdd(&curs[r & 127], 1);
            csr_src[p] = (int)(r >> 7);
        }
    }
}

// ---------------- fused layer 1: Agg(x) + matvec + tanh + bf16 pack ------------
// one block per bucket: edge-parallel gather of x (L2-resident, 1.6MB) into
// LDS acc[128][4] via float atomics, then Yp = pack(tanh(Ax@W1+b1)*dinv).
__global__ void __launch_bounds__(256) k_aggmm1(const uint32* __restrict__ data,
                                                const int* __restrict__ cnt,
                                                const float* __restrict__ x,
                                                const float* __restrict__ dinv,
                                                const float* __restrict__ W1,
                                                const float* __restrict__ b1,
                                                uint32* __restrict__ Yp) {
    __shared__ float acc[128][4];
    __shared__ float w1s[4][128];
    __shared__ float b1s[128];
    __shared__ int scnt[8];
    int bkt = blockIdx.x;
    int t = threadIdx.x;
    if (t < 128) {
        acc[t][0] = 0.f; acc[t][1] = 0.f; acc[t][2] = 0.f; acc[t][3] = 0.f;
        b1s[t] = b1[t];
    }
    if (t >= 128 && t < 136) scnt[t - 128] = min(cnt[bkt * 8 + (t - 128)], SUB);
    ((float*)w1s)[t] = W1[t];
    ((float*)w1s)[256 + t] = W1[256 + t];
    __syncthreads();
    for (int c = 0; c < 8; ++c) {
        int base = bkt * CAP + c * SUB, n = scnt[c];
        for (int j = t; j < n; j += 256) {
            uint32 r = data[base + j];
            int s = (int)(r >> 7), dl = (int)(r & 127);
            float w = dinv[s];
            const float4 xv = *(const float4*)(x + (size_t)s * INF);
            atomicAdd(&acc[dl][0], xv.x * w);
            atomicAdd(&acc[dl][1], xv.y * w);
            atomicAdd(&acc[dl][2], xv.z * w);
            atomicAdd(&acc[dl][3], xv.w * w);
        }
    }
    __syncthreads();
    int nbase = bkt * 128;
    #pragma unroll
    for (int rep = 0; rep < 32; ++rep) {
        int flat = rep * 256 + t;       // 8192 = 128 nodes * 64 uint outputs
        int node = flat >> 6;
        int fp = flat & 63;
        int gi = nbase + node;
        if (gi < NN) {
            float di = dinv[gi];
            const float4 xi = *(const float4*)(x + (size_t)gi * INF);
            float a0 = (acc[node][0] + xi.x * di) * di;
            float a1 = (acc[node][1] + xi.y * di) * di;
            float a2 = (acc[node][2] + xi.z * di) * di;
            float a3 = (acc[node][3] + xi.w * di) * di;
            int f0 = fp * 2;
            float d0 = b1s[f0]     + a0 * w1s[0][f0]     + a1 * w1s[1][f0]
                                   + a2 * w1s[2][f0]     + a3 * w1s[3][f0];
            float d1 = b1s[f0 + 1] + a0 * w1s[0][f0 + 1] + a1 * w1s[1][f0 + 1]
                                   + a2 * w1s[2][f0 + 1] + a3 * w1s[3][f0 + 1];
            Yp[(size_t)gi * 64 + fp] = pack_bf16(tanhf(d0) * di, tanhf(d1) * di);
        }
    }
}

// ---------------- layer 2 gather: Z = dinv[i] * (sum Yp[s] + Yp[i]) -------------
// one wave per node; per edge one coalesced 256B row read; unroll x4 for MLP.
__global__ void k_aggy(const uint32* __restrict__ Yp, const int* __restrict__ csr_off,
                       const int* __restrict__ csr_cnt, const int* __restrict__ csr_src,
                       const float* __restrict__ dinv, float* __restrict__ Z) {
    int wid = threadIdx.x >> 6;
    int lane = threadIdx.x & 63;
    int i = blockIdx.x * 4 + wid;
    if (i >= NN) return;
    int b = csr_off[i];
    int e = b + csr_cnt[i];
    float a0 = 0.f, a1 = 0.f;
    int j = b;
    for (; j + 4 <= e; j += 4) {
        int s0 = csr_src[j];
        int s1 = csr_src[j + 1];
        int s2 = csr_src[j + 2];
        int s3 = csr_src[j + 3];
        uint32 v0 = Yp[(size_t)s0 * 64 + lane];
        uint32 v1 = Yp[(size_t)s1 * 64 + lane];
        uint32 v2 = Yp[(size_t)s2 * 64 + lane];
        uint32 v3 = Yp[(size_t)s3 * 64 + lane];
        a0 += __uint_as_float(v0 << 16);
        a1 += __uint_as_float(v0 & 0xffff0000u);
        a0 += __uint_as_float(v1 << 16);
        a1 += __uint_as_float(v1 & 0xffff0000u);
        a0 += __uint_as_float(v2 << 16);
        a1 += __uint_as_float(v2 & 0xffff0000u);
        a0 += __uint_as_float(v3 << 16);
        a1 += __uint_as_float(v3 & 0xffff0000u);
    }
    for (; j < e; ++j) {
        uint32 v = Yp[(size_t)csr_src[j] * 64 + lane];
        a0 += __uint_as_float(v << 16);
        a1 += __uint_as_float(v & 0xffff0000u);
    }
    uint32 vi = Yp[(size_t)i * 64 + lane];
    a0 += __uint_as_float(vi << 16);
    a1 += __uint_as_float(vi & 0xffff0000u);
    float di = dinv[i];
    *(float2*)(Z + (size_t)i * H + lane * 2) = make_float2(a0 * di, a1 * di);
}

// ---------------- O = tanh(Z @ W2 + b2), fused mean-pool accumulation ------------
__global__ void __launch_bounds__(256) k_mm2pool(
    const float* __restrict__ Z, const float* __restrict__ W2,
    const float* __restrict__ b2, float* __restrict__ pooled) {
    __shared__ float w2s[H][64];   // [k][feat-in-half], 32 KB
    __shared__ float zt[H][64];    // [k][node^swz],     32 KB

    int tid = threadIdx.x;
    int fhalf = blockIdx.x & 1;

    #pragma unroll
    for (int rep = 0; rep < 8; ++rep) {
        int flat = rep * 256 + tid;
        int k = flat >> 4;
        int j4 = (flat & 15) * 4;
        float4 v = *(const float4*)(W2 + (size_t)k * H + fhalf * 64 + j4);
        *(float4*)(&w2s[k][j4]) = v;
    }

    int wid = tid >> 6, lane = tid & 63;
    int ng = lane & 15, fg = lane >> 4;
    int fbase = fhalf * 64 + wid * 16 + fg * 4;
    int fcol  = wid * 16 + fg * 4;

    float bias[4];
    #pragma unroll
    for (int b = 0; b < 4; ++b) bias[b] = b2[fbase + b];

    float pool[4] = {0.f, 0.f, 0.f, 0.f};

    const int ntiles = (NN + 63) >> 6;           // 1563
    for (int tile = blockIdx.x >> 1; tile < ntiles; tile += (int)(gridDim.x >> 1)) {
        __syncthreads();
        int nbase = tile << 6;
        #pragma unroll
        for (int rep = 0; rep < 8; ++rep) {
            int flat = rep * 256 + tid;
            int node = flat >> 5;
            int k4 = (flat & 31) * 4;
            int gi = nbase + node;
            float4 v = make_float4(0.f, 0.f, 0.f, 0.f);
            if (gi < NN) v = *(const float4*)(Z + (size_t)gi * H + k4);
            #pragma unroll
            for (int i = 0; i < 4; ++i) {
                int k = k4 + i;
                int col = node ^ (((k >> 2) & 15) << 2);
                zt[k][col] = (&v.x)[i];
            }
        }
        __syncthreads();

        float acc[4][4];
        #pragma unroll
        for (int a = 0; a < 4; ++a)
            #pragma unroll
            for (int b = 0; b < 4; ++b) acc[a][b] = bias[b];

        #pragma unroll 4
        for (int k = 0; k < H; ++k) {
            int zc = (ng * 4) ^ (((k >> 2) & 15) << 2);
            const float4 zv = *(const float4*)(&zt[k][zc]);
            const float4 wv = *(const float4*)(&w2s[k][fcol]);
            acc[0][0] += zv.x * wv.x; acc[0][1] += zv.x * wv.y; acc[0][2] += zv.x * wv.z; acc[0][3] += zv.x * wv.w;
            acc[1][0] += zv.y * wv.x; acc[1][1] += zv.y * wv.y; acc[1][2] += zv.y * wv.z; acc[1][3] += zv.y * wv.w;
            acc[2][0] += zv.z * wv.x; acc[2][1] += zv.z * wv.y; acc[2][2] += zv.z * wv.z; acc[2][3] += zv.z * wv.w;
            acc[3][0] += zv.w * wv.x; acc[3][1] += zv.w * wv.y; acc[3][2] += zv.w * wv.z; acc[3][3] += zv.w * wv.w;
        }

        #pragma unroll
        for (int a = 0; a < 4; ++a) {
            bool valid = (nbase + ng * 4 + a) < NN;
            #pragma unroll
            for (int b = 0; b < 4; ++b) {
                pool[b] += valid ? tanhf(acc[a][b]) : 0.f;
            }
        }
    }

    #pragma unroll
    for (int b = 0; b < 4; ++b) {
        float t = pool[b];
        t += __shfl_xor(t, 1, 64);
        t += __shfl_xor(t, 2, 64);
        t += __shfl_xor(t, 4, 64);
        t += __shfl_xor(t, 8, 64);
        if (ng == 0) atomicAdd(&pooled[fbase + b], t);
    }
}

// ---------------- final: vel = (pooled/N) @ Wfc + bfc, mask by in_size ----------
__global__ void k_final(const float* __restrict__ pooled, const float* __restrict__ Wfc,
                        const float* __restrict__ bfc, const int* __restrict__ in_size,
                        float* __restrict__ out) {
    int t = threadIdx.x;
    if (t >= RR * OUTF) return;
    const float invn = 1.0f / (float)NN;
    float a = bfc[t];
    for (int k = 0; k < H; ++k) a += (pooled[k] * invn) * Wfc[k * (RR * OUTF) + t];
    int r = t >> 1;
    out[t] = (r < *in_size) ? a : 0.f;
}

extern "C" void kernel_launch(void* const* d_in, const int* in_sizes, int n_in,
                              void* d_out, int out_size, void* d_ws, size_t ws_size,
                              hipStream_t stream) {
    const float* x   = (const float*)d_in[0];
    const int*   ei  = (const int*)d_in[1];     // [2, E]
    const float* W1  = (const float*)d_in[3];
    const float* b1  = (const float*)d_in[4];
    const float* W2  = (const float*)d_in[5];
    const float* b2  = (const float*)d_in[6];
    const float* Wfc = (const float*)d_in[7];
    const float* bfc = (const float*)d_in[8];
    float* out = (float*)d_out;

    const int* srcp = ei;
    const int* dstp = ei + NE;

    // workspace layout (512B aligned chunks)
    char* ws = (char*)d_ws;
    size_t off = 0;
    auto alloc = [&](size_t bytes) { void* p = ws + off; off += (bytes + 511) & ~(size_t)511; return p; };
    int*    cnt     = (int*)alloc((size_t)NB * 8 * 4);
    uint32* data    = (uint32*)alloc((size_t)NB * CAP * 4);   // 12.8 MB
    float*  dinv    = (float*)alloc((size_t)NN * 4);
    int*    csr_off = (int*)alloc((size_t)NN * 4);
    int*    csr_cnt = (int*)alloc((size_t)NN * 4);
    int*    csr_src = (int*)alloc((size_t)NB * CAP * 4);      // 12.8 MB (bucket-regional)
    uint32* Yp      = (uint32*)alloc((size_t)NN * 64 * 4);    // packed bf16, premult dinv
    float*  Z       = (float*)alloc((size_t)NN * H * 4);
    float*  pooled  = (float*)alloc(H * 4);
    int*    in_size = (int*)alloc(64);
    (void)off; (void)ws_size; (void)in_sizes; (void)n_in; (void)out_size;

    const int nbN = (NN + 255) / 256;        // 391
    const int nbE = (NE + 255) / 256;        // 6250
    const int nbW = (NN + 3) / 4;            // 4 waves (nodes) per block

    hipMemsetAsync(cnt, 0, (size_t)NB * 8 * 4, stream);
    k_init_small<<<1, 256, 0, stream>>>(pooled, in_size);
    k_init_nodes<<<nbN, 256, 0, stream>>>(x, in_size);
    k_scatter<<<nbE, 256, 0, stream>>>(srcp, dstp, cnt, data);
    k_build<<<NB, 256, 0, stream>>>(data, cnt, csr_off, csr_cnt, csr_src, dinv);
    k_aggmm1<<<NB, 256, 0, stream>>>(data, cnt, x, dinv, W1, b1, Yp);
    k_aggy<<<nbW, 256, 0, stream>>>(Yp, csr_off, csr_cnt, csr_src, dinv, Z);
    k_mm2pool<<<512, 256, 0, stream>>>(Z, W2, b2, pooled);
    k_final<<<1, 64, 0, stream>>>(pooled, Wfc, bfc, in_size, out);
}

// Round 8
// 361.070 us; speedup vs baseline: 1.3950x; 1.1265x over previous
//
#include <hip/hip_runtime.h>

#define NN 100000
#define NE 1600000
#define INF 4
#define H 128
#define RR 20
#define OUTF 2
#define NB 782            // buckets of 128 nodes: ceil(100000/128)
#define CAP 4096          // record slots per bucket (mean 2048)
#define SUB 512           // per-(bucket, xcd-proxy) sub-segment (mean 256, +16 sigma)

typedef unsigned int uint32;
typedef __attribute__((ext_vector_type(8))) short short8;   // 8 bf16 (4 VGPR) MFMA A/B frag
typedef __attribute__((ext_vector_type(4))) float f32x4;    // MFMA C/D frag

// round-to-nearest-even bf16 pack: x -> low 16, y -> high 16
__device__ inline uint32 pack_bf16(float x, float y) {
    uint32 ux = __float_as_uint(x);
    uint32 uy = __float_as_uint(y);
    ux = (ux + 0x7fffu + ((ux >> 16) & 1u)) >> 16;
    uy = (uy + 0x7fffu + ((uy >> 16) & 1u)) & 0xffff0000u;
    return ux | uy;
}

// ---------------- init ----------------
__global__ void k_init_small(float* __restrict__ pooled, int* __restrict__ in_size) {
    int t = threadIdx.x;
    if (t < H) pooled[t] = 0.f;
    if (t == H) *in_size = 0;
}

__global__ void k_init_nodes(const float* __restrict__ x, int* __restrict__ in_size) {
    int i = blockIdx.x * 256 + threadIdx.x;
    bool pred = false;
    if (i < NN) {
        float x0 = x[(size_t)i * INF + 0];
        float x1 = x[(size_t)i * INF + 1];
        pred = (x0 != 0.f) && (x1 != 0.f);
    }
    unsigned long long m = __ballot(pred);
    if ((threadIdx.x & 63) == 0) {
        int c = __popcll(m);
        if (c) atomicAdd(in_size, c);
    }
}

// ---------------- one-pass bucketed scatter ----------------
__global__ void k_scatter(const int* __restrict__ src, const int* __restrict__ dst,
                          int* __restrict__ cnt, uint32* __restrict__ data) {
    int e = blockIdx.x * 256 + threadIdx.x;
    if (e < NE) {
        int s = src[e], d = dst[e];
        int bkt = d >> 7, px = blockIdx.x & 7;
        int p = atomicAdd(&cnt[bkt * 8 + px], 1);
        if (p < SUB)   // cannot trigger (+16 sigma); guards OOB
            data[(size_t)bkt * CAP + px * SUB + p] = ((uint32)s << 7) | (uint32)(d & 127);
    }
}

// one block per bucket: histogram -> csr_off/csr_cnt/dinv + node-sorted csr_src.
__global__ void __launch_bounds__(256) k_build(const uint32* __restrict__ data,
                                               const int* __restrict__ cnt,
                                               int* __restrict__ csr_off,
                                               int* __restrict__ csr_cnt,
                                               int* __restrict__ csr_src,
                                               float* __restrict__ dinv) {
    __shared__ int hist[128], pfx[128], curs[128], scnt[8];
    int bkt = blockIdx.x;
    int t = threadIdx.x;
    if (t < 128) hist[t] = 0;
    if (t >= 128 && t < 136) scnt[t - 128] = min(cnt[bkt * 8 + (t - 128)], SUB);
    __syncthreads();
    for (int c = 0; c < 8; ++c) {
        int base = bkt * CAP + c * SUB, n = scnt[c];
        for (int j = t; j < n; j += 256)
            atomicAdd(&hist[data[base + j] & 127], 1);
    }
    __syncthreads();
    if (t < 128) pfx[t] = hist[t];
    __syncthreads();
    for (int off = 1; off < 128; off <<= 1) {
        int u = (t < 128 && t >= off) ? pfx[t - off] : 0;
        __syncthreads();
        if (t < 128) pfx[t] += u;
        __syncthreads();
    }
    int nodeCount = min(128, NN - bkt * 128);
    if (t < nodeCount) {
        int excl = bkt * CAP + pfx[t] - hist[t];
        csr_off[bkt * 128 + t] = excl;
        csr_cnt[bkt * 128 + t] = hist[t];
        curs[t] = excl;
        dinv[bkt * 128 + t] = rsqrtf((float)(hist[t] + 1));
    }
    __syncthreads();
    for (int c = 0; c < 8; ++c) {
        int base = bkt * CAP + c * SUB, n = scnt[c];
        for (int j = t; j < n; j += 256) {
            uint32 r = data[base + j];
            int p = atomicAdd(&curs[r & 127], 1);
            csr_src[p] = (int)(r >> 7);
        }
    }
}

// ---------------- fused layer 1: Agg(x) + matvec + tanh + bf16 pack ------------
__global__ void __launch_bounds__(256) k_aggmm1(const uint32* __restrict__ data,
                                                const int* __restrict__ cnt,
                                                const float* __restrict__ x,
                                                const float* __restrict__ dinv,
                                                const float* __restrict__ W1,
                                                const float* __restrict__ b1,
                                                uint32* __restrict__ Yp) {
    __shared__ float acc[128][4];
    __shared__ float w1s[4][128];
    __shared__ float b1s[128];
    __shared__ int scnt[8];
    int bkt = blockIdx.x;
    int t = threadIdx.x;
    if (t < 128) {
        acc[t][0] = 0.f; acc[t][1] = 0.f; acc[t][2] = 0.f; acc[t][3] = 0.f;
        b1s[t] = b1[t];
    }
    if (t >= 128 && t < 136) scnt[t - 128] = min(cnt[bkt * 8 + (t - 128)], SUB);
    ((float*)w1s)[t] = W1[t];
    ((float*)w1s)[256 + t] = W1[256 + t];
    __syncthreads();
    for (int c = 0; c < 8; ++c) {
        int base = bkt * CAP + c * SUB, n = scnt[c];
        for (int j = t; j < n; j += 256) {
            uint32 r = data[base + j];
            int s = (int)(r >> 7), dl = (int)(r & 127);
            float w = dinv[s];
            const float4 xv = *(const float4*)(x + (size_t)s * INF);
            atomicAdd(&acc[dl][0], xv.x * w);
            atomicAdd(&acc[dl][1], xv.y * w);
            atomicAdd(&acc[dl][2], xv.z * w);
            atomicAdd(&acc[dl][3], xv.w * w);
        }
    }
    __syncthreads();
    int nbase = bkt * 128;
    #pragma unroll
    for (int rep = 0; rep < 32; ++rep) {
        int flat = rep * 256 + t;       // 8192 = 128 nodes * 64 uint outputs
        int node = flat >> 6;
        int fp = flat & 63;
        int gi = nbase + node;
        if (gi < NN) {
            float di = dinv[gi];
            const float4 xi = *(const float4*)(x + (size_t)gi * INF);
            float a0 = (acc[node][0] + xi.x * di) * di;
            float a1 = (acc[node][1] + xi.y * di) * di;
            float a2 = (acc[node][2] + xi.z * di) * di;
            float a3 = (acc[node][3] + xi.w * di) * di;
            int f0 = fp * 2;
            float d0 = b1s[f0]     + a0 * w1s[0][f0]     + a1 * w1s[1][f0]
                                   + a2 * w1s[2][f0]     + a3 * w1s[3][f0];
            float d1 = b1s[f0 + 1] + a0 * w1s[0][f0 + 1] + a1 * w1s[1][f0 + 1]
                                   + a2 * w1s[2][f0 + 1] + a3 * w1s[3][f0 + 1];
            Yp[(size_t)gi * 64 + fp] = pack_bf16(tanhf(d0) * di, tanhf(d1) * di);
        }
    }
}

// ---------------- layer 2 gather: Zp = bf16( dinv[i] * (sum Yp[s] + Yp[i]) ) ----
// one wave per node; per edge one coalesced 256B row read; unroll x4 for MLP.
// Output packed bf16 (feeds MFMA mm2): 25.6 MB instead of 51.2.
__global__ void k_aggy(const uint32* __restrict__ Yp, const int* __restrict__ csr_off,
                       const int* __restrict__ csr_cnt, const int* __restrict__ csr_src,
                       const float* __restrict__ dinv, uint32* __restrict__ Zp) {
    int wid = threadIdx.x >> 6;
    int lane = threadIdx.x & 63;
    int i = blockIdx.x * 4 + wid;
    if (i >= NN) return;
    int b = csr_off[i];
    int e = b + csr_cnt[i];
    float a0 = 0.f, a1 = 0.f;
    int j = b;
    for (; j + 4 <= e; j += 4) {
        int s0 = csr_src[j];
        int s1 = csr_src[j + 1];
        int s2 = csr_src[j + 2];
        int s3 = csr_src[j + 3];
        uint32 v0 = Yp[(size_t)s0 * 64 + lane];
        uint32 v1 = Yp[(size_t)s1 * 64 + lane];
        uint32 v2 = Yp[(size_t)s2 * 64 + lane];
        uint32 v3 = Yp[(size_t)s3 * 64 + lane];
        a0 += __uint_as_float(v0 << 16);
        a1 += __uint_as_float(v0 & 0xffff0000u);
        a0 += __uint_as_float(v1 << 16);
        a1 += __uint_as_float(v1 & 0xffff0000u);
        a0 += __uint_as_float(v2 << 16);
        a1 += __uint_as_float(v2 & 0xffff0000u);
        a0 += __uint_as_float(v3 << 16);
        a1 += __uint_as_float(v3 & 0xffff0000u);
    }
    for (; j < e; ++j) {
        uint32 v = Yp[(size_t)csr_src[j] * 64 + lane];
        a0 += __uint_as_float(v << 16);
        a1 += __uint_as_float(v & 0xffff0000u);
    }
    uint32 vi = Yp[(size_t)i * 64 + lane];
    a0 += __uint_as_float(vi << 16);
    a1 += __uint_as_float(vi & 0xffff0000u);
    float di = dinv[i];
    Zp[(size_t)i * 64 + lane] = pack_bf16(a0 * di, a1 * di);
}

// ---------------- O = tanh(Zp @ W2 + b2) via MFMA, fused mean-pool --------------
// Block = 4 waves; wave w owns feats [32w, 32w+32) with its W2 slice in registers
// as hi/lo bf16 split (W2 = W2h + W2l, quantization error ~2^-18). A-frags read
// directly from global (16-node tiles, NN % 16 == 0 -> no masking); 4 waves share
// each tile via L1. mfma_f32_16x16x32_bf16: A lane m=lane&15, k=8*(lane>>4)+i
// (8 consecutive bf16 = one b128 load); C col=lane&15=feat, rows sum into pool.
__global__ void __launch_bounds__(256) k_mm2pool(
    const uint32* __restrict__ Zp, const float* __restrict__ W2,
    const float* __restrict__ b2, float* __restrict__ pooled) {
    int tid = threadIdx.x;
    int wid = tid >> 6, lane = tid & 63;
    int nsub = lane & 15;     // M (node) / N (feat) index within 16
    int kg = lane >> 4;       // k-group
    int fbase = wid * 32;

    // load W2 slice into registers, hi/lo bf16 split (once per kernel)
    short8 Bh[2][4], Bl[2][4];
    #pragma unroll
    for (int c = 0; c < 2; ++c) {
        #pragma unroll
        for (int ks = 0; ks < 4; ++ks) {
            short8 h, l;
            #pragma unroll
            for (int i = 0; i < 8; ++i) {
                float w = W2[(size_t)(ks * 32 + kg * 8 + i) * H + (fbase + c * 16 + nsub)];
                uint32 uw = __float_as_uint(w);
                uint32 uh = (uw + 0x7fffu + ((uw >> 16) & 1u)) & 0xffff0000u;
                float wl = w - __uint_as_float(uh);
                uint32 uwl = __float_as_uint(wl);
                uint32 ul = (uwl + 0x7fffu + ((uwl >> 16) & 1u)) & 0xffff0000u;
                h[i] = (short)(uh >> 16);
                l[i] = (short)(ul >> 16);
            }
            Bh[c][ks] = h;
            Bl[c][ks] = l;
        }
    }
    float bb0 = b2[fbase + nsub];
    float bb1 = b2[fbase + 16 + nsub];
    float pool0 = 0.f, pool1 = 0.f;

    const int ntiles = NN / 16;          // 6250 exact
    const int stride = (int)gridDim.x;
    int t = (int)blockIdx.x;

    short8 A[4];
    if (t < ntiles) {
        const uint32* rp = Zp + (size_t)(t * 16 + nsub) * 64 + kg * 4;
        #pragma unroll
        for (int ks = 0; ks < 4; ++ks) A[ks] = *(const short8*)(rp + ks * 16);
    }
    while (t < ntiles) {
        int tn = t + stride;
        short8 An[4];
        if (tn < ntiles) {
            const uint32* rp = Zp + (size_t)(tn * 16 + nsub) * 64 + kg * 4;
            #pragma unroll
            for (int ks = 0; ks < 4; ++ks) An[ks] = *(const short8*)(rp + ks * 16);
        }
        {
            f32x4 acch0 = {0.f,0.f,0.f,0.f}, accl0 = {0.f,0.f,0.f,0.f};
            f32x4 acch1 = {0.f,0.f,0.f,0.f}, accl1 = {0.f,0.f,0.f,0.f};
            #pragma unroll
            for (int ks = 0; ks < 4; ++ks) {
                acch0 = __builtin_amdgcn_mfma_f32_16x16x32_bf16(A[ks], Bh[0][ks], acch0, 0, 0, 0);
                accl0 = __builtin_amdgcn_mfma_f32_16x16x32_bf16(A[ks], Bl[0][ks], accl0, 0, 0, 0);
                acch1 = __builtin_amdgcn_mfma_f32_16x16x32_bf16(A[ks], Bh[1][ks], acch1, 0, 0, 0);
                accl1 = __builtin_amdgcn_mfma_f32_16x16x32_bf16(A[ks], Bl[1][ks], accl1, 0, 0, 0);
            }
            #pragma unroll
            for (int r = 0; r < 4; ++r) {
                pool0 += tanhf(acch0[r] + accl0[r] + bb0);
                pool1 += tanhf(acch1[r] + accl1[r] + bb1);
            }
        }
        #pragma unroll
        for (int ks = 0; ks < 4; ++ks) A[ks] = An[ks];
        t = tn;
    }

    // reduce over the 4 kg-duplicated lanes (rows already summed into pool regs)
    pool0 += __shfl_xor(pool0, 16, 64);
    pool0 += __shfl_xor(pool0, 32, 64);
    pool1 += __shfl_xor(pool1, 16, 64);
    pool1 += __shfl_xor(pool1, 32, 64);
    if (kg == 0) {
        atomicAdd(&pooled[fbase + nsub], pool0);
        atomicAdd(&pooled[fbase + 16 + nsub], pool1);
    }
}

// ---------------- final: vel = (pooled/N) @ Wfc + bfc, mask by in_size ----------
__global__ void k_final(const float* __restrict__ pooled, const float* __restrict__ Wfc,
                        const float* __restrict__ bfc, const int* __restrict__ in_size,
                        float* __restrict__ out) {
    int t = threadIdx.x;
    if (t >= RR * OUTF) return;
    const float invn = 1.0f / (float)NN;
    float a = bfc[t];
    for (int k = 0; k < H; ++k) a += (pooled[k] * invn) * Wfc[k * (RR * OUTF) + t];
    int r = t >> 1;
    out[t] = (r < *in_size) ? a : 0.f;
}

extern "C" void kernel_launch(void* const* d_in, const int* in_sizes, int n_in,
                              void* d_out, int out_size, void* d_ws, size_t ws_size,
                              hipStream_t stream) {
    const float* x   = (const float*)d_in[0];
    const int*   ei  = (const int*)d_in[1];     // [2, E]
    const float* W1  = (const float*)d_in[3];
    const float* b1  = (const float*)d_in[4];
    const float* W2  = (const float*)d_in[5];
    const float* b2  = (const float*)d_in[6];
    const float* Wfc = (const float*)d_in[7];
    const float* bfc = (const float*)d_in[8];
    float* out = (float*)d_out;

    const int* srcp = ei;
    const int* dstp = ei + NE;

    // workspace layout (512B aligned chunks)
    char* ws = (char*)d_ws;
    size_t off = 0;
    auto alloc = [&](size_t bytes) { void* p = ws + off; off += (bytes + 511) & ~(size_t)511; return p; };
    int*    cnt     = (int*)alloc((size_t)NB * 8 * 4);
    uint32* data    = (uint32*)alloc((size_t)NB * CAP * 4);   // 12.8 MB
    float*  dinv    = (float*)alloc((size_t)NN * 4);
    int*    csr_off = (int*)alloc((size_t)NN * 4);
    int*    csr_cnt = (int*)alloc((size_t)NN * 4);
    int*    csr_src = (int*)alloc((size_t)NB * CAP * 4);      // 12.8 MB (bucket-regional)
    uint32* Yp      = (uint32*)alloc((size_t)NN * 64 * 4);    // packed bf16, premult dinv
    uint32* Zp      = (uint32*)alloc((size_t)NN * 64 * 4);    // packed bf16 layer-2 agg
    float*  pooled  = (float*)alloc(H * 4);
    int*    in_size = (int*)alloc(64);
    (void)off; (void)ws_size; (void)in_sizes; (void)n_in; (void)out_size;

    const int nbN = (NN + 255) / 256;        // 391
    const int nbE = (NE + 255) / 256;        // 6250
    const int nbW = (NN + 3) / 4;            // 4 waves (nodes) per block

    hipMemsetAsync(cnt, 0, (size_t)NB * 8 * 4, stream);
    k_init_small<<<1, 256, 0, stream>>>(pooled, in_size);
    k_init_nodes<<<nbN, 256, 0, stream>>>(x, in_size);
    k_scatter<<<nbE, 256, 0, stream>>>(srcp, dstp, cnt, data);
    k_build<<<NB, 256, 0, stream>>>(data, cnt, csr_off, csr_cnt, csr_src, dinv);
    k_aggmm1<<<NB, 256, 0, stream>>>(data, cnt, x, dinv, W1, b1, Yp);
    k_aggy<<<nbW, 256, 0, stream>>>(Yp, csr_off, csr_cnt, csr_src, dinv, Zp);
    k_mm2pool<<<512, 256, 0, stream>>>(Zp, W2, b2, pooled);
    k_final<<<1, 64, 0, stream>>>(pooled, Wfc, bfc, in_size, out);
}

// Round 9
// 353.284 us; speedup vs baseline: 1.4258x; 1.0220x over previous
//
#include <hip/hip_runtime.h>

#define NN 100000
#define NE 1600000
#define INF 4
#define H 128
#define RR 20
#define OUTF 2
#define NB 782            // buckets of 128 nodes: ceil(100000/128)
#define SUB 512           // per-(bucket, xcd) sub-segment capacity
#define OSUB 2048         // per-bucket overflow segment (correctness under ANY dispatch)
#define CAPB (8 * SUB + OSUB)   // 6144 record slots per bucket

typedef unsigned int uint32;
typedef __attribute__((ext_vector_type(8))) short short8;   // 8 bf16 (4 VGPR) MFMA A/B frag
typedef __attribute__((ext_vector_type(4))) float f32x4;    // MFMA C/D frag

// round-to-nearest-even bf16 pack: x -> low 16, y -> high 16
__device__ inline uint32 pack_bf16(float x, float y) {
    uint32 ux = __float_as_uint(x);
    uint32 uy = __float_as_uint(y);
    ux = (ux + 0x7fffu + ((ux >> 16) & 1u)) >> 16;
    uy = (uy + 0x7fffu + ((uy >> 16) & 1u)) & 0xffff0000u;
    return ux | uy;
}

// ---------------- init ----------------
__global__ void k_init_small(float* __restrict__ pooled, int* __restrict__ in_size) {
    int t = threadIdx.x;
    if (t < H) pooled[t] = 0.f;
    if (t == H) *in_size = 0;
}

__global__ void k_init_nodes(const float* __restrict__ x, int* __restrict__ in_size) {
    int i = blockIdx.x * 256 + threadIdx.x;
    bool pred = false;
    if (i < NN) {
        float x0 = x[(size_t)i * INF + 0];
        float x1 = x[(size_t)i * INF + 1];
        pred = (x0 != 0.f) && (x1 != 0.f);
    }
    unsigned long long m = __ballot(pred);
    if ((threadIdx.x & 63) == 0) {
        int c = __popcll(m);
        if (c) atomicAdd(in_size, c);
    }
}

// ---------------- one-pass bucketed scatter, XCD-local sub-segments -------------
// px = REAL XCD id (s_getreg HW_REG_XCC_ID) -> each XCD appends only to its own
// 1.6 MB region (L2-resident lines accumulate 16 records -> ~1x write amp).
// Overflow segment makes capacity correct under ANY workgroup->XCD mapping.
__global__ void k_scatter(const int* __restrict__ src, const int* __restrict__ dst,
                          int* __restrict__ cnt, uint32* __restrict__ data) {
    int e = blockIdx.x * 256 + threadIdx.x;
    if (e >= NE) return;
    int xcc;
    asm volatile("s_getreg_b32 %0, hwreg(HW_REG_XCC_ID)" : "=s"(xcc));
    int px = xcc & 7;
    int s = src[e], d = dst[e];
    int bkt = d >> 7;
    uint32 rec = ((uint32)s << 7) | (uint32)(d & 127);
    int p = atomicAdd(&cnt[bkt * 16 + px], 1);
    if (p < SUB) {
        data[(size_t)bkt * CAPB + px * SUB + p] = rec;
    } else {
        int q = atomicAdd(&cnt[bkt * 16 + 8], 1);
        if (q < OSUB) data[(size_t)bkt * CAPB + 8 * SUB + q] = rec;
    }
}

// one block per bucket: histogram -> csr_off/csr_cnt/dinv + node-sorted csr_src.
__global__ void __launch_bounds__(256) k_build(const uint32* __restrict__ data,
                                               const int* __restrict__ cnt,
                                               int* __restrict__ csr_off,
                                               int* __restrict__ csr_cnt,
                                               int* __restrict__ csr_src,
                                               float* __restrict__ dinv) {
    __shared__ int hist[128], pfx[128], curs[128], scnt[9];
    int bkt = blockIdx.x;
    int t = threadIdx.x;
    if (t < 128) hist[t] = 0;
    if (t >= 128 && t < 137) {
        int c = t - 128;
        scnt[c] = min(cnt[bkt * 16 + c], (c == 8) ? OSUB : SUB);
    }
    __syncthreads();
    for (int c = 0; c < 9; ++c) {
        int base = bkt * CAPB + c * SUB, n = scnt[c];   // c==8: 8*SUB = overflow base
        for (int j = t; j < n; j += 256)
            atomicAdd(&hist[data[base + j] & 127], 1);
    }
    __syncthreads();
    if (t < 128) pfx[t] = hist[t];
    __syncthreads();
    for (int off = 1; off < 128; off <<= 1) {
        int u = (t < 128 && t >= off) ? pfx[t - off] : 0;
        __syncthreads();
        if (t < 128) pfx[t] += u;
        __syncthreads();
    }
    int nodeCount = min(128, NN - bkt * 128);
    if (t < nodeCount) {
        int excl = bkt * CAPB + pfx[t] - hist[t];
        csr_off[bkt * 128 + t] = excl;
        csr_cnt[bkt * 128 + t] = hist[t];
        curs[t] = excl;
        dinv[bkt * 128 + t] = rsqrtf((float)(hist[t] + 1));
    }
    __syncthreads();
    for (int c = 0; c < 9; ++c) {
        int base = bkt * CAPB + c * SUB, n = scnt[c];
        for (int j = t; j < n; j += 256) {
            uint32 r = data[base + j];
            int p = atomicAdd(&curs[r & 127], 1);
            csr_src[p] = (int)(r >> 7);
        }
    }
}

// ---------------- fused layer 1: Agg(x) + matvec + tanh + bf16 pack ------------
__global__ void __launch_bounds__(256) k_aggmm1(const uint32* __restrict__ data,
                                                const int* __restrict__ cnt,
                                                const float* __restrict__ x,
                                                const float* __restrict__ dinv,
                                                const float* __restrict__ W1,
                                                const float* __restrict__ b1,
                                                uint32* __restrict__ Yp) {
    __shared__ float acc[128][4];
    __shared__ float w1s[4][128];
    __shared__ float b1s[128];
    __shared__ int scnt[9];
    int bkt = blockIdx.x;
    int t = threadIdx.x;
    if (t < 128) {
        acc[t][0] = 0.f; acc[t][1] = 0.f; acc[t][2] = 0.f; acc[t][3] = 0.f;
        b1s[t] = b1[t];
    }
    if (t >= 128 && t < 137) {
        int c = t - 128;
        scnt[c] = min(cnt[bkt * 16 + c], (c == 8) ? OSUB : SUB);
    }
    ((float*)w1s)[t] = W1[t];
    ((float*)w1s)[256 + t] = W1[256 + t];
    __syncthreads();
    for (int c = 0; c < 9; ++c) {
        int base = bkt * CAPB + c * SUB, n = scnt[c];
        for (int j = t; j < n; j += 256) {
            uint32 r = data[base + j];
            int s = (int)(r >> 7), dl = (int)(r & 127);
            float w = dinv[s];
            const float4 xv = *(const float4*)(x + (size_t)s * INF);
            atomicAdd(&acc[dl][0], xv.x * w);
            atomicAdd(&acc[dl][1], xv.y * w);
            atomicAdd(&acc[dl][2], xv.z * w);
            atomicAdd(&acc[dl][3], xv.w * w);
        }
    }
    __syncthreads();
    int nbase = bkt * 128;
    #pragma unroll
    for (int rep = 0; rep < 32; ++rep) {
        int flat = rep * 256 + t;       // 8192 = 128 nodes * 64 uint outputs
        int node = flat >> 6;
        int fp = flat & 63;
        int gi = nbase + node;
        if (gi < NN) {
            float di = dinv[gi];
            const float4 xi = *(const float4*)(x + (size_t)gi * INF);
            float a0 = (acc[node][0] + xi.x * di) * di;
            float a1 = (acc[node][1] + xi.y * di) * di;
            float a2 = (acc[node][2] + xi.z * di) * di;
            float a3 = (acc[node][3] + xi.w * di) * di;
            int f0 = fp * 2;
            float d0 = b1s[f0]     + a0 * w1s[0][f0]     + a1 * w1s[1][f0]
                                   + a2 * w1s[2][f0]     + a3 * w1s[3][f0];
            float d1 = b1s[f0 + 1] + a0 * w1s[0][f0 + 1] + a1 * w1s[1][f0 + 1]
                                   + a2 * w1s[2][f0 + 1] + a3 * w1s[3][f0 + 1];
            Yp[(size_t)gi * 64 + fp] = pack_bf16(tanhf(d0) * di, tanhf(d1) * di);
        }
    }
}

// ---------------- layer 2 gather: Zp = bf16( dinv[i]*(sum Yp[s] + Yp[i]) ) ------
// one wave per node; lane = (edge-group eg=lane>>4, 16B segment seg=lane&15):
// one dwordx4 wave-load fetches FOUR edges' row-chunks (1 KB) -> 4x fewer load
// issues; unroll x2 for 2 loads in flight. shfl-reduce over eg at the end.
__global__ void k_aggy(const uint32* __restrict__ Yp, const int* __restrict__ csr_off,
                       const int* __restrict__ csr_cnt, const int* __restrict__ csr_src,
                       const float* __restrict__ dinv, uint32* __restrict__ Zp) {
    int wid = threadIdx.x >> 6;
    int lane = threadIdx.x & 63;
    int i = blockIdx.x * 4 + wid;
    if (i >= NN) return;
    int b = csr_off[i];
    int n = csr_cnt[i];
    int eg = lane >> 4, seg = lane & 15;

    float a[8] = {0.f, 0.f, 0.f, 0.f, 0.f, 0.f, 0.f, 0.f};
    int j = 0;
    for (; j + 8 <= n; j += 8) {       // all lanes valid: j+4+eg <= j+7 <= n-1
        int s0 = csr_src[b + j + eg];
        int s1 = csr_src[b + j + 4 + eg];
        uint4 v0 = *(const uint4*)(Yp + (size_t)s0 * 64 + seg * 4);
        uint4 v1 = *(const uint4*)(Yp + (size_t)s1 * 64 + seg * 4);
        a[0] += __uint_as_float(v0.x << 16); a[1] += __uint_as_float(v0.x & 0xffff0000u);
        a[2] += __uint_as_float(v0.y << 16); a[3] += __uint_as_float(v0.y & 0xffff0000u);
        a[4] += __uint_as_float(v0.z << 16); a[5] += __uint_as_float(v0.z & 0xffff0000u);
        a[6] += __uint_as_float(v0.w << 16); a[7] += __uint_as_float(v0.w & 0xffff0000u);
        a[0] += __uint_as_float(v1.x << 16); a[1] += __uint_as_float(v1.x & 0xffff0000u);
        a[2] += __uint_as_float(v1.y << 16); a[3] += __uint_as_float(v1.y & 0xffff0000u);
        a[4] += __uint_as_float(v1.z << 16); a[5] += __uint_as_float(v1.z & 0xffff0000u);
        a[6] += __uint_as_float(v1.w << 16); a[7] += __uint_as_float(v1.w & 0xffff0000u);
    }
    for (; j < n; j += 4) {
        int jj = j + eg;
        bool valid = jj < n;
        int s = valid ? csr_src[b + jj] : i;   // safe address; contribution masked
        uint4 v = *(const uint4*)(Yp + (size_t)s * 64 + seg * 4);
        if (valid) {
            a[0] += __uint_as_float(v.x << 16); a[1] += __uint_as_float(v.x & 0xffff0000u);
            a[2] += __uint_as_float(v.y << 16); a[3] += __uint_as_float(v.y & 0xffff0000u);
            a[4] += __uint_as_float(v.z << 16); a[5] += __uint_as_float(v.z & 0xffff0000u);
            a[6] += __uint_as_float(v.w << 16); a[7] += __uint_as_float(v.w & 0xffff0000u);
        }
    }
    // self-loop (once)
    {
        uint4 v = *(const uint4*)(Yp + (size_t)i * 64 + seg * 4);
        if (eg == 0) {
            a[0] += __uint_as_float(v.x << 16); a[1] += __uint_as_float(v.x & 0xffff0000u);
            a[2] += __uint_as_float(v.y << 16); a[3] += __uint_as_float(v.y & 0xffff0000u);
            a[4] += __uint_as_float(v.z << 16); a[5] += __uint_as_float(v.z & 0xffff0000u);
            a[6] += __uint_as_float(v.w << 16); a[7] += __uint_as_float(v.w & 0xffff0000u);
        }
    }
    // reduce across the 4 edge-groups (butterfly; all lanes end with full sums)
    #pragma unroll
    for (int m = 0; m < 8; ++m) {
        a[m] += __shfl_xor(a[m], 16, 64);
        a[m] += __shfl_xor(a[m], 32, 64);
    }
    if (eg == 0) {
        float di = dinv[i];
        uint4 o;
        o.x = pack_bf16(a[0] * di, a[1] * di);
        o.y = pack_bf16(a[2] * di, a[3] * di);
        o.z = pack_bf16(a[4] * di, a[5] * di);
        o.w = pack_bf16(a[6] * di, a[7] * di);
        *(uint4*)(Zp + (size_t)i * 64 + seg * 4) = o;
    }
}

// ---------------- O = tanh(Zp @ W2 + b2) via MFMA, fused mean-pool --------------
__global__ void __launch_bounds__(256) k_mm2pool(
    const uint32* __restrict__ Zp, const float* __restrict__ W2,
    const float* __restrict__ b2, float* __restrict__ pooled) {
    int tid = threadIdx.x;
    int wid = tid >> 6, lane = tid & 63;
    int nsub = lane & 15;     // M (node) / N (feat) index within 16
    int kg = lane >> 4;       // k-group
    int fbase = wid * 32;

    // load W2 slice into registers, hi/lo bf16 split (once per kernel)
    short8 Bh[2][4], Bl[2][4];
    #pragma unroll
    for (int c = 0; c < 2; ++c) {
        #pragma unroll
        for (int ks = 0; ks < 4; ++ks) {
            short8 h, l;
            #pragma unroll
            for (int i = 0; i < 8; ++i) {
                float w = W2[(size_t)(ks * 32 + kg * 8 + i) * H + (fbase + c * 16 + nsub)];
                uint32 uw = __float_as_uint(w);
                uint32 uh = (uw + 0x7fffu + ((uw >> 16) & 1u)) & 0xffff0000u;
                float wl = w - __uint_as_float(uh);
                uint32 uwl = __float_as_uint(wl);
                uint32 ul = (uwl + 0x7fffu + ((uwl >> 16) & 1u)) & 0xffff0000u;
                h[i] = (short)(uh >> 16);
                l[i] = (short)(ul >> 16);
            }
            Bh[c][ks] = h;
            Bl[c][ks] = l;
        }
    }
    float bb0 = b2[fbase + nsub];
    float bb1 = b2[fbase + 16 + nsub];
    float pool0 = 0.f, pool1 = 0.f;

    const int ntiles = NN / 16;          // 6250 exact
    const int stride = (int)gridDim.x;
    int t = (int)blockIdx.x;

    short8 A[4];
    if (t < ntiles) {
        const uint32* rp = Zp + (size_t)(t * 16 + nsub) * 64 + kg * 4;
        #pragma unroll
        for (int ks = 0; ks < 4; ++ks) A[ks] = *(const short8*)(rp + ks * 16);
    }
    while (t < ntiles) {
        int tn = t + stride;
        short8 An[4];
        if (tn < ntiles) {
            const uint32* rp = Zp + (size_t)(tn * 16 + nsub) * 64 + kg * 4;
            #pragma unroll
            for (int ks = 0; ks < 4; ++ks) An[ks] = *(const short8*)(rp + ks * 16);
        }
        {
            f32x4 acch0 = {0.f,0.f,0.f,0.f}, accl0 = {0.f,0.f,0.f,0.f};
            f32x4 acch1 = {0.f,0.f,0.f,0.f}, accl1 = {0.f,0.f,0.f,0.f};
            #pragma unroll
            for (int ks = 0; ks < 4; ++ks) {
                acch0 = __builtin_amdgcn_mfma_f32_16x16x32_bf16(A[ks], Bh[0][ks], acch0, 0, 0, 0);
                accl0 = __builtin_amdgcn_mfma_f32_16x16x32_bf16(A[ks], Bl[0][ks], accl0, 0, 0, 0);
                acch1 = __builtin_amdgcn_mfma_f32_16x16x32_bf16(A[ks], Bh[1][ks], acch1, 0, 0, 0);
                accl1 = __builtin_amdgcn_mfma_f32_16x16x32_bf16(A[ks], Bl[1][ks], accl1, 0, 0, 0);
            }
            #pragma unroll
            for (int r = 0; r < 4; ++r) {
                pool0 += tanhf(acch0[r] + accl0[r] + bb0);
                pool1 += tanhf(acch1[r] + accl1[r] + bb1);
            }
        }
        #pragma unroll
        for (int ks = 0; ks < 4; ++ks) A[ks] = An[ks];
        t = tn;
    }

    // reduce over the 4 kg-duplicated lanes (rows already summed into pool regs)
    pool0 += __shfl_xor(pool0, 16, 64);
    pool0 += __shfl_xor(pool0, 32, 64);
    pool1 += __shfl_xor(pool1, 16, 64);
    pool1 += __shfl_xor(pool1, 32, 64);
    if (kg == 0) {
        atomicAdd(&pooled[fbase + nsub], pool0);
        atomicAdd(&pooled[fbase + 16 + nsub], pool1);
    }
}

// ---------------- final: vel = (pooled/N) @ Wfc + bfc, mask by in_size ----------
__global__ void k_final(const float* __restrict__ pooled, const float* __restrict__ Wfc,
                        const float* __restrict__ bfc, const int* __restrict__ in_size,
                        float* __restrict__ out) {
    int t = threadIdx.x;
    if (t >= RR * OUTF) return;
    const float invn = 1.0f / (float)NN;
    float a = bfc[t];
    for (int k = 0; k < H; ++k) a += (pooled[k] * invn) * Wfc[k * (RR * OUTF) + t];
    int r = t >> 1;
    out[t] = (r < *in_size) ? a : 0.f;
}

extern "C" void kernel_launch(void* const* d_in, const int* in_sizes, int n_in,
                              void* d_out, int out_size, void* d_ws, size_t ws_size,
                              hipStream_t stream) {
    const float* x   = (const float*)d_in[0];
    const int*   ei  = (const int*)d_in[1];     // [2, E]
    const float* W1  = (const float*)d_in[3];
    const float* b1  = (const float*)d_in[4];
    const float* W2  = (const float*)d_in[5];
    const float* b2  = (const float*)d_in[6];
    const float* Wfc = (const float*)d_in[7];
    const float* bfc = (const float*)d_in[8];
    float* out = (float*)d_out;

    const int* srcp = ei;
    const int* dstp = ei + NE;

    // workspace layout (512B aligned chunks)
    char* ws = (char*)d_ws;
    size_t off = 0;
    auto alloc = [&](size_t bytes) { void* p = ws + off; off += (bytes + 511) & ~(size_t)511; return p; };
    int*    cnt     = (int*)alloc((size_t)NB * 16 * 4);
    uint32* data    = (uint32*)alloc((size_t)NB * CAPB * 4);  // 19.2 MB
    float*  dinv    = (float*)alloc((size_t)NN * 4);
    int*    csr_off = (int*)alloc((size_t)NN * 4);
    int*    csr_cnt = (int*)alloc((size_t)NN * 4);
    int*    csr_src = (int*)alloc((size_t)NB * CAPB * 4);     // 19.2 MB (bucket-regional)
    uint32* Yp      = (uint32*)alloc((size_t)NN * 64 * 4);    // packed bf16, premult dinv
    uint32* Zp      = (uint32*)alloc((size_t)NN * 64 * 4);    // packed bf16 layer-2 agg
    float*  pooled  = (float*)alloc(H * 4);
    int*    in_size = (int*)alloc(64);
    (void)off; (void)ws_size; (void)in_sizes; (void)n_in; (void)out_size;

    const int nbN = (NN + 255) / 256;        // 391
    const int nbE = (NE + 255) / 256;        // 6250
    const int nbW = (NN + 3) / 4;            // 4 waves (nodes) per block

    hipMemsetAsync(cnt, 0, (size_t)NB * 16 * 4, stream);
    k_init_small<<<1, 256, 0, stream>>>(pooled, in_size);
    k_init_nodes<<<nbN, 256, 0, stream>>>(x, in_size);
    k_scatter<<<nbE, 256, 0, stream>>>(srcp, dstp, cnt, data);
    k_build<<<NB, 256, 0, stream>>>(data, cnt, csr_off, csr_cnt, csr_src, dinv);
    k_aggmm1<<<NB, 256, 0, stream>>>(data, cnt, x, dinv, W1, b1, Yp);
    k_aggy<<<nbW, 256, 0, stream>>>(Yp, csr_off, csr_cnt, csr_src, dinv, Zp);
    k_mm2pool<<<512, 256, 0, stream>>>(Zp, W2, b2, pooled);
    k_final<<<1, 64, 0, stream>>>(pooled, Wfc, bfc, in_size, out);
}

// Round 10
// 319.884 us; speedup vs baseline: 1.5746x; 1.1044x over previous
//
#include <hip/hip_runtime.h>

#define NN 100000
#define NE 1600000
#define INF 4
#define H 128
#define RR 20
#define OUTF 2
#define NB 782            // buckets of 128 nodes: ceil(100000/128)
#define NBP 784           // padded row stride for hist/offs matrices
#define EPB 16384         // edges per partition block
#define NBLK ((NE + EPB - 1) / EPB)   // 98

typedef unsigned int uint32;
typedef __attribute__((ext_vector_type(8))) short short8;   // 8 bf16 (4 VGPR) MFMA A/B frag
typedef __attribute__((ext_vector_type(4))) float f32x4;    // MFMA C/D frag

// round-to-nearest-even bf16 pack: x -> low 16, y -> high 16
__device__ inline uint32 pack_bf16(float x, float y) {
    uint32 ux = __float_as_uint(x);
    uint32 uy = __float_as_uint(y);
    ux = (ux + 0x7fffu + ((ux >> 16) & 1u)) >> 16;
    uy = (uy + 0x7fffu + ((uy >> 16) & 1u)) & 0xffff0000u;
    return ux | uy;
}

// ---------------- init ----------------
__global__ void k_init_small(float* __restrict__ pooled, int* __restrict__ in_size) {
    int t = threadIdx.x;
    if (t < H) pooled[t] = 0.f;
    if (t == H) *in_size = 0;
}

__global__ void k_init_nodes(const float* __restrict__ x, int* __restrict__ in_size) {
    int i = blockIdx.x * 256 + threadIdx.x;
    bool pred = false;
    if (i < NN) {
        float x0 = x[(size_t)i * INF + 0];
        float x1 = x[(size_t)i * INF + 1];
        pred = (x0 != 0.f) && (x1 != 0.f);
    }
    unsigned long long m = __ballot(pred);
    if ((threadIdx.x & 63) == 0) {
        int c = __popcll(m);
        if (c) atomicAdd(in_size, c);
    }
}

// ---------------- counting-sort partition (LDS atomics only) --------------------
// Phase A: per-partition-block LDS histogram of dst buckets.
__global__ void __launch_bounds__(256) k_hist(const int* __restrict__ dst,
                                              int* __restrict__ histG) {
    __shared__ int h[NB];
    int b = blockIdx.x, t = threadIdx.x;
    for (int i = t; i < NB; i += 256) h[i] = 0;
    __syncthreads();
    int e0 = b * EPB, eend = min(e0 + EPB, NE);
    for (int e = e0 + t; e < eend; e += 256) atomicAdd(&h[dst[e] >> 7], 1);
    __syncthreads();
    for (int i = t; i < NB; i += 256) histG[b * NBP + i] = h[i];
}

// Phase B1: per-bucket exclusive prefix over partition blocks + bucket totals.
// thread per bucket; loads/stores coalesced across consecutive buckets.
__global__ void k_btotoffs(const int* __restrict__ histG, int* __restrict__ offs,
                           int* __restrict__ btot) {
    int bkt = blockIdx.x * 256 + threadIdx.x;
    if (bkt >= NB) return;
    int run = 0;
    for (int j = 0; j < NBLK; ++j) {
        int v = histG[j * NBP + bkt];
        offs[j * NBP + bkt] = run;
        run += v;
    }
    btot[bkt] = run;
}

// Phase B2: exclusive scan of bucket totals -> bucket bases (+ sentinel NE).
__global__ void __launch_bounds__(1024) k_bbase(const int* __restrict__ btot,
                                                int* __restrict__ bbase) {
    __shared__ int sm[1024];
    int t = threadIdx.x;
    int v = (t < NB) ? btot[t] : 0;
    sm[t] = v;
    __syncthreads();
    for (int off = 1; off < 1024; off <<= 1) {
        int u = (t >= off) ? sm[t - off] : 0;
        __syncthreads();
        sm[t] += u;
        __syncthreads();
    }
    if (t < NB) bbase[t] = sm[t] - v;
    if (t == 0) bbase[NB] = NE;
}

// Phase C: scatter records to deterministic slots; only LDS atomics.
__global__ void __launch_bounds__(256) k_scat2(const int* __restrict__ src,
                                               const int* __restrict__ dst,
                                               const int* __restrict__ offs,
                                               const int* __restrict__ bbase,
                                               uint32* __restrict__ data) {
    __shared__ int cur[NB];
    int b = blockIdx.x, t = threadIdx.x;
    for (int i = t; i < NB; i += 256) cur[i] = offs[b * NBP + i] + bbase[i];
    __syncthreads();
    int e0 = b * EPB, eend = min(e0 + EPB, NE);
    for (int e = e0 + t; e < eend; e += 256) {
        int s = src[e], d = dst[e];
        int p = atomicAdd(&cur[d >> 7], 1);
        data[p] = ((uint32)s << 7) | (uint32)(d & 127);
    }
}

// one block per bucket: histogram -> csr_off/csr_cnt/dinv + node-sorted csr_src.
__global__ void __launch_bounds__(256) k_build(const uint32* __restrict__ data,
                                               const int* __restrict__ bbase,
                                               int* __restrict__ csr_off,
                                               int* __restrict__ csr_cnt,
                                               int* __restrict__ csr_src,
                                               float* __restrict__ dinv) {
    __shared__ int hist[128], pfx[128], curs[128];
    int bkt = blockIdx.x;
    int t = threadIdx.x;
    int rbeg = bbase[bkt], rend = bbase[bkt + 1];
    if (t < 128) hist[t] = 0;
    __syncthreads();
    for (int j = rbeg + t; j < rend; j += 256)
        atomicAdd(&hist[data[j] & 127], 1);
    __syncthreads();
    if (t < 128) pfx[t] = hist[t];
    __syncthreads();
    for (int off = 1; off < 128; off <<= 1) {
        int u = (t < 128 && t >= off) ? pfx[t - off] : 0;
        __syncthreads();
        if (t < 128) pfx[t] += u;
        __syncthreads();
    }
    int nodeCount = min(128, NN - bkt * 128);
    if (t < nodeCount) {
        int excl = rbeg + pfx[t] - hist[t];
        csr_off[bkt * 128 + t] = excl;
        csr_cnt[bkt * 128 + t] = hist[t];
        curs[t] = excl;
        dinv[bkt * 128 + t] = rsqrtf((float)(hist[t] + 1));
    }
    __syncthreads();
    for (int j = rbeg + t; j < rend; j += 256) {
        uint32 r = data[j];
        int p = atomicAdd(&curs[r & 127], 1);
        csr_src[p] = (int)(r >> 7);
    }
}

// ---------------- fused layer 1: Agg(x) + matvec + tanh + bf16 pack ------------
__global__ void __launch_bounds__(256) k_aggmm1(const uint32* __restrict__ data,
                                                const int* __restrict__ bbase,
                                                const float* __restrict__ x,
                                                const float* __restrict__ dinv,
                                                const float* __restrict__ W1,
                                                const float* __restrict__ b1,
                                                uint32* __restrict__ Yp) {
    __shared__ float acc[128][4];
    __shared__ float w1s[4][128];
    __shared__ float b1s[128];
    int bkt = blockIdx.x;
    int t = threadIdx.x;
    if (t < 128) {
        acc[t][0] = 0.f; acc[t][1] = 0.f; acc[t][2] = 0.f; acc[t][3] = 0.f;
        b1s[t] = b1[t];
    }
    ((float*)w1s)[t] = W1[t];
    ((float*)w1s)[256 + t] = W1[256 + t];
    int rbeg = bbase[bkt], rend = bbase[bkt + 1];
    __syncthreads();
    for (int j = rbeg + t; j < rend; j += 256) {
        uint32 r = data[j];
        int s = (int)(r >> 7), dl = (int)(r & 127);
        float w = dinv[s];
        const float4 xv = *(const float4*)(x + (size_t)s * INF);
        atomicAdd(&acc[dl][0], xv.x * w);
        atomicAdd(&acc[dl][1], xv.y * w);
        atomicAdd(&acc[dl][2], xv.z * w);
        atomicAdd(&acc[dl][3], xv.w * w);
    }
    __syncthreads();
    int nbase = bkt * 128;
    #pragma unroll
    for (int rep = 0; rep < 32; ++rep) {
        int flat = rep * 256 + t;       // 8192 = 128 nodes * 64 uint outputs
        int node = flat >> 6;
        int fp = flat & 63;
        int gi = nbase + node;
        if (gi < NN) {
            float di = dinv[gi];
            const float4 xi = *(const float4*)(x + (size_t)gi * INF);
            float a0 = (acc[node][0] + xi.x * di) * di;
            float a1 = (acc[node][1] + xi.y * di) * di;
            float a2 = (acc[node][2] + xi.z * di) * di;
            float a3 = (acc[node][3] + xi.w * di) * di;
            int f0 = fp * 2;
            float d0 = b1s[f0]     + a0 * w1s[0][f0]     + a1 * w1s[1][f0]
                                   + a2 * w1s[2][f0]     + a3 * w1s[3][f0];
            float d1 = b1s[f0 + 1] + a0 * w1s[0][f0 + 1] + a1 * w1s[1][f0 + 1]
                                   + a2 * w1s[2][f0 + 1] + a3 * w1s[3][f0 + 1];
            Yp[(size_t)gi * 64 + fp] = pack_bf16(tanhf(d0) * di, tanhf(d1) * di);
        }
    }
}

// ---------------- layer 2 gather: Zp = bf16( dinv[i]*(sum Yp[s] + Yp[i]) ) ------
// one wave per node; lane = (edge-group eg=lane>>4, 16B segment seg=lane&15):
// one dwordx4 wave-load fetches FOUR edges' row-chunks (1 KB); unroll x2.
__global__ void k_aggy(const uint32* __restrict__ Yp, const int* __restrict__ csr_off,
                       const int* __restrict__ csr_cnt, const int* __restrict__ csr_src,
                       const float* __restrict__ dinv, uint32* __restrict__ Zp) {
    int wid = threadIdx.x >> 6;
    int lane = threadIdx.x & 63;
    int i = blockIdx.x * 4 + wid;
    if (i >= NN) return;
    int b = csr_off[i];
    int n = csr_cnt[i];
    int eg = lane >> 4, seg = lane & 15;

    float a[8] = {0.f, 0.f, 0.f, 0.f, 0.f, 0.f, 0.f, 0.f};
    int j = 0;
    for (; j + 8 <= n; j += 8) {       // all lanes valid: j+4+eg <= j+7 <= n-1
        int s0 = csr_src[b + j + eg];
        int s1 = csr_src[b + j + 4 + eg];
        uint4 v0 = *(const uint4*)(Yp + (size_t)s0 * 64 + seg * 4);
        uint4 v1 = *(const uint4*)(Yp + (size_t)s1 * 64 + seg * 4);
        a[0] += __uint_as_float(v0.x << 16); a[1] += __uint_as_float(v0.x & 0xffff0000u);
        a[2] += __uint_as_float(v0.y << 16); a[3] += __uint_as_float(v0.y & 0xffff0000u);
        a[4] += __uint_as_float(v0.z << 16); a[5] += __uint_as_float(v0.z & 0xffff0000u);
        a[6] += __uint_as_float(v0.w << 16); a[7] += __uint_as_float(v0.w & 0xffff0000u);
        a[0] += __uint_as_float(v1.x << 16); a[1] += __uint_as_float(v1.x & 0xffff0000u);
        a[2] += __uint_as_float(v1.y << 16); a[3] += __uint_as_float(v1.y & 0xffff0000u);
        a[4] += __uint_as_float(v1.z << 16); a[5] += __uint_as_float(v1.z & 0xffff0000u);
        a[6] += __uint_as_float(v1.w << 16); a[7] += __uint_as_float(v1.w & 0xffff0000u);
    }
    for (; j < n; j += 4) {
        int jj = j + eg;
        bool valid = jj < n;
        int s = valid ? csr_src[b + jj] : i;   // safe address; contribution masked
        uint4 v = *(const uint4*)(Yp + (size_t)s * 64 + seg * 4);
        if (valid) {
            a[0] += __uint_as_float(v.x << 16); a[1] += __uint_as_float(v.x & 0xffff0000u);
            a[2] += __uint_as_float(v.y << 16); a[3] += __uint_as_float(v.y & 0xffff0000u);
            a[4] += __uint_as_float(v.z << 16); a[5] += __uint_as_float(v.z & 0xffff0000u);
            a[6] += __uint_as_float(v.w << 16); a[7] += __uint_as_float(v.w & 0xffff0000u);
        }
    }
    // self-loop (once)
    {
        uint4 v = *(const uint4*)(Yp + (size_t)i * 64 + seg * 4);
        if (eg == 0) {
            a[0] += __uint_as_float(v.x << 16); a[1] += __uint_as_float(v.x & 0xffff0000u);
            a[2] += __uint_as_float(v.y << 16); a[3] += __uint_as_float(v.y & 0xffff0000u);
            a[4] += __uint_as_float(v.z << 16); a[5] += __uint_as_float(v.z & 0xffff0000u);
            a[6] += __uint_as_float(v.w << 16); a[7] += __uint_as_float(v.w & 0xffff0000u);
        }
    }
    // reduce across the 4 edge-groups (butterfly; all lanes end with full sums)
    #pragma unroll
    for (int m = 0; m < 8; ++m) {
        a[m] += __shfl_xor(a[m], 16, 64);
        a[m] += __shfl_xor(a[m], 32, 64);
    }
    if (eg == 0) {
        float di = dinv[i];
        uint4 o;
        o.x = pack_bf16(a[0] * di, a[1] * di);
        o.y = pack_bf16(a[2] * di, a[3] * di);
        o.z = pack_bf16(a[4] * di, a[5] * di);
        o.w = pack_bf16(a[6] * di, a[7] * di);
        *(uint4*)(Zp + (size_t)i * 64 + seg * 4) = o;
    }
}

// ---------------- O = tanh(Zp @ W2 + b2) via MFMA, fused mean-pool --------------
__global__ void __launch_bounds__(256) k_mm2pool(
    const uint32* __restrict__ Zp, const float* __restrict__ W2,
    const float* __restrict__ b2, float* __restrict__ pooled) {
    int tid = threadIdx.x;
    int wid = tid >> 6, lane = tid & 63;
    int nsub = lane & 15;     // M (node) / N (feat) index within 16
    int kg = lane >> 4;       // k-group
    int fbase = wid * 32;

    // load W2 slice into registers, hi/lo bf16 split (once per kernel)
    short8 Bh[2][4], Bl[2][4];
    #pragma unroll
    for (int c = 0; c < 2; ++c) {
        #pragma unroll
        for (int ks = 0; ks < 4; ++ks) {
            short8 h, l;
            #pragma unroll
            for (int i = 0; i < 8; ++i) {
                float w = W2[(size_t)(ks * 32 + kg * 8 + i) * H + (fbase + c * 16 + nsub)];
                uint32 uw = __float_as_uint(w);
                uint32 uh = (uw + 0x7fffu + ((uw >> 16) & 1u)) & 0xffff0000u;
                float wl = w - __uint_as_float(uh);
                uint32 uwl = __float_as_uint(wl);
                uint32 ul = (uwl + 0x7fffu + ((uwl >> 16) & 1u)) & 0xffff0000u;
                h[i] = (short)(uh >> 16);
                l[i] = (short)(ul >> 16);
            }
            Bh[c][ks] = h;
            Bl[c][ks] = l;
        }
    }
    float bb0 = b2[fbase + nsub];
    float bb1 = b2[fbase + 16 + nsub];
    float pool0 = 0.f, pool1 = 0.f;

    const int ntiles = NN / 16;          // 6250 exact
    const int stride = (int)gridDim.x;
    int t = (int)blockIdx.x;

    short8 A[4];
    if (t < ntiles) {
        const uint32* rp = Zp + (size_t)(t * 16 + nsub) * 64 + kg * 4;
        #pragma unroll
        for (int ks = 0; ks < 4; ++ks) A[ks] = *(const short8*)(rp + ks * 16);
    }
    while (t < ntiles) {
        int tn = t + stride;
        short8 An[4];
        if (tn < ntiles) {
            const uint32* rp = Zp + (size_t)(tn * 16 + nsub) * 64 + kg * 4;
            #pragma unroll
            for (int ks = 0; ks < 4; ++ks) An[ks] = *(const short8*)(rp + ks * 16);
        }
        {
            f32x4 acch0 = {0.f,0.f,0.f,0.f}, accl0 = {0.f,0.f,0.f,0.f};
            f32x4 acch1 = {0.f,0.f,0.f,0.f}, accl1 = {0.f,0.f,0.f,0.f};
            #pragma unroll
            for (int ks = 0; ks < 4; ++ks) {
                acch0 = __builtin_amdgcn_mfma_f32_16x16x32_bf16(A[ks], Bh[0][ks], acch0, 0, 0, 0);
                accl0 = __builtin_amdgcn_mfma_f32_16x16x32_bf16(A[ks], Bl[0][ks], accl0, 0, 0, 0);
                acch1 = __builtin_amdgcn_mfma_f32_16x16x32_bf16(A[ks], Bh[1][ks], acch1, 0, 0, 0);
                accl1 = __builtin_amdgcn_mfma_f32_16x16x32_bf16(A[ks], Bl[1][ks], accl1, 0, 0, 0);
            }
            #pragma unroll
            for (int r = 0; r < 4; ++r) {
                pool0 += tanhf(acch0[r] + accl0[r] + bb0);
                pool1 += tanhf(acch1[r] + accl1[r] + bb1);
            }
        }
        #pragma unroll
        for (int ks = 0; ks < 4; ++ks) A[ks] = An[ks];
        t = tn;
    }

    // reduce over the 4 kg-duplicated lanes (rows already summed into pool regs)
    pool0 += __shfl_xor(pool0, 16, 64);
    pool0 += __shfl_xor(pool0, 32, 64);
    pool1 += __shfl_xor(pool1, 16, 64);
    pool1 += __shfl_xor(pool1, 32, 64);
    if (kg == 0) {
        atomicAdd(&pooled[fbase + nsub], pool0);
        atomicAdd(&pooled[fbase + 16 + nsub], pool1);
    }
}

// ---------------- final: vel = (pooled/N) @ Wfc + bfc, mask by in_size ----------
__global__ void k_final(const float* __restrict__ pooled, const float* __restrict__ Wfc,
                        const float* __restrict__ bfc, const int* __restrict__ in_size,
                        float* __restrict__ out) {
    int t = threadIdx.x;
    if (t >= RR * OUTF) return;
    const float invn = 1.0f / (float)NN;
    float a = bfc[t];
    for (int k = 0; k < H; ++k) a += (pooled[k] * invn) * Wfc[k * (RR * OUTF) + t];
    int r = t >> 1;
    out[t] = (r < *in_size) ? a : 0.f;
}

extern "C" void kernel_launch(void* const* d_in, const int* in_sizes, int n_in,
                              void* d_out, int out_size, void* d_ws, size_t ws_size,
                              hipStream_t stream) {
    const float* x   = (const float*)d_in[0];
    const int*   ei  = (const int*)d_in[1];     // [2, E]
    const float* W1  = (const float*)d_in[3];
    const float* b1  = (const float*)d_in[4];
    const float* W2  = (const float*)d_in[5];
    const float* b2  = (const float*)d_in[6];
    const float* Wfc = (const float*)d_in[7];
    const float* bfc = (const float*)d_in[8];
    float* out = (float*)d_out;

    const int* srcp = ei;
    const int* dstp = ei + NE;

    // workspace layout (512B aligned chunks)
    char* ws = (char*)d_ws;
    size_t off = 0;
    auto alloc = [&](size_t bytes) { void* p = ws + off; off += (bytes + 511) & ~(size_t)511; return p; };
    int*    histG   = (int*)alloc((size_t)NBLK * NBP * 4);    // 307 KB
    int*    offs    = (int*)alloc((size_t)NBLK * NBP * 4);    // 307 KB
    int*    btot    = (int*)alloc((size_t)NB * 4);
    int*    bbase   = (int*)alloc(((size_t)NB + 1) * 4);
    uint32* data    = (uint32*)alloc((size_t)NE * 4);         // 6.4 MB exact
    float*  dinv    = (float*)alloc((size_t)NN * 4);
    int*    csr_off = (int*)alloc((size_t)NN * 4);
    int*    csr_cnt = (int*)alloc((size_t)NN * 4);
    int*    csr_src = (int*)alloc((size_t)NE * 4);            // 6.4 MB
    uint32* Yp      = (uint32*)alloc((size_t)NN * 64 * 4);    // packed bf16, premult dinv
    uint32* Zp      = (uint32*)alloc((size_t)NN * 64 * 4);    // packed bf16 layer-2 agg
    float*  pooled  = (float*)alloc(H * 4);
    int*    in_size = (int*)alloc(64);
    (void)off; (void)ws_size; (void)in_sizes; (void)n_in; (void)out_size;

    const int nbN = (NN + 255) / 256;        // 391
    const int nbW = (NN + 3) / 4;            // 4 waves (nodes) per block

    k_init_small<<<1, 256, 0, stream>>>(pooled, in_size);
    k_init_nodes<<<nbN, 256, 0, stream>>>(x, in_size);
    k_hist<<<NBLK, 256, 0, stream>>>(dstp, histG);
    k_btotoffs<<<(NB + 255) / 256, 256, 0, stream>>>(histG, offs, btot);
    k_bbase<<<1, 1024, 0, stream>>>(btot, bbase);
    k_scat2<<<NBLK, 256, 0, stream>>>(srcp, dstp, offs, bbase, data);
    k_build<<<NB, 256, 0, stream>>>(data, bbase, csr_off, csr_cnt, csr_src, dinv);
    k_aggmm1<<<NB, 256, 0, stream>>>(data, bbase, x, dinv, W1, b1, Yp);
    k_aggy<<<nbW, 256, 0, stream>>>(Yp, csr_off, csr_cnt, csr_src, dinv, Zp);
    k_mm2pool<<<512, 256, 0, stream>>>(Zp, W2, b2, pooled);
    k_final<<<1, 64, 0, stream>>>(pooled, Wfc, bfc, in_size, out);
}

// Round 11
// 319.345 us; speedup vs baseline: 1.5773x; 1.0017x over previous
//
#include <hip/hip_runtime.h>
#include <hip/hip_fp16.h>

#define NN 100000
#define NE 1600000
#define INF 4
#define H 128
#define RR 20
#define OUTF 2
#define NB 782            // buckets of 128 nodes: ceil(100000/128)
#define NBP 784           // padded row stride for hist/offs matrices
#define EPB 16384         // edges per partition block
#define NBLK ((NE + EPB - 1) / EPB)   // 98

typedef unsigned int uint32;
typedef __attribute__((ext_vector_type(8))) short short8;   // 8 f16 (4 VGPR) MFMA A/B frag
typedef __attribute__((ext_vector_type(4))) float f32x4;    // MFMA C/D frag

// pack two floats to fp16 pair (RNE): x -> low 16, y -> high 16
__device__ inline uint32 pack_f16(float x, float y) {
    return (uint32)__half_as_ushort(__float2half(x)) |
           ((uint32)__half_as_ushort(__float2half(y)) << 16);
}
__device__ inline __half2 bc_h2(uint32 u) {
    union { uint32 u; __half2 h; } c; c.u = u; return c.h;
}

// ---------------- init ----------------
__global__ void k_init_small(float* __restrict__ pooled, int* __restrict__ in_size) {
    int t = threadIdx.x;
    if (t < H) pooled[t] = 0.f;
    if (t == H) *in_size = 0;
}

__global__ void k_init_nodes(const float* __restrict__ x, int* __restrict__ in_size) {
    int i = blockIdx.x * 256 + threadIdx.x;
    bool pred = false;
    if (i < NN) {
        float x0 = x[(size_t)i * INF + 0];
        float x1 = x[(size_t)i * INF + 1];
        pred = (x0 != 0.f) && (x1 != 0.f);
    }
    unsigned long long m = __ballot(pred);
    if ((threadIdx.x & 63) == 0) {
        int c = __popcll(m);
        if (c) atomicAdd(in_size, c);
    }
}

// ---------------- counting-sort partition (LDS atomics only) --------------------
__global__ void __launch_bounds__(256) k_hist(const int* __restrict__ dst,
                                              int* __restrict__ histG) {
    __shared__ int h[NB];
    int b = blockIdx.x, t = threadIdx.x;
    for (int i = t; i < NB; i += 256) h[i] = 0;
    __syncthreads();
    int e0 = b * EPB, eend = min(e0 + EPB, NE);
    for (int e = e0 + t; e < eend; e += 256) atomicAdd(&h[dst[e] >> 7], 1);
    __syncthreads();
    for (int i = t; i < NB; i += 256) histG[b * NBP + i] = h[i];
}

__global__ void k_btotoffs(const int* __restrict__ histG, int* __restrict__ offs,
                           int* __restrict__ btot) {
    int bkt = blockIdx.x * 256 + threadIdx.x;
    if (bkt >= NB) return;
    int run = 0;
    for (int j = 0; j < NBLK; ++j) {
        int v = histG[j * NBP + bkt];
        offs[j * NBP + bkt] = run;
        run += v;
    }
    btot[bkt] = run;
}

__global__ void __launch_bounds__(1024) k_bbase(const int* __restrict__ btot,
                                                int* __restrict__ bbase) {
    __shared__ int sm[1024];
    int t = threadIdx.x;
    int v = (t < NB) ? btot[t] : 0;
    sm[t] = v;
    __syncthreads();
    for (int off = 1; off < 1024; off <<= 1) {
        int u = (t >= off) ? sm[t - off] : 0;
        __syncthreads();
        sm[t] += u;
        __syncthreads();
    }
    if (t < NB) bbase[t] = sm[t] - v;
    if (t == 0) bbase[NB] = NE;
}

__global__ void __launch_bounds__(256) k_scat2(const int* __restrict__ src,
                                               const int* __restrict__ dst,
                                               const int* __restrict__ offs,
                                               const int* __restrict__ bbase,
                                               uint32* __restrict__ data) {
    __shared__ int cur[NB];
    int b = blockIdx.x, t = threadIdx.x;
    for (int i = t; i < NB; i += 256) cur[i] = offs[b * NBP + i] + bbase[i];
    __syncthreads();
    int e0 = b * EPB, eend = min(e0 + EPB, NE);
    for (int e = e0 + t; e < eend; e += 256) {
        int s = src[e], d = dst[e];
        int p = atomicAdd(&cur[d >> 7], 1);
        data[p] = ((uint32)s << 7) | (uint32)(d & 127);
    }
}

// one block per bucket: histogram -> csr_off/csr_cnt/dinv + node-sorted csr_src.
__global__ void __launch_bounds__(256) k_build(const uint32* __restrict__ data,
                                               const int* __restrict__ bbase,
                                               int* __restrict__ csr_off,
                                               int* __restrict__ csr_cnt,
                                               int* __restrict__ csr_src,
                                               float* __restrict__ dinv) {
    __shared__ int hist[128], pfx[128], curs[128];
    int bkt = blockIdx.x;
    int t = threadIdx.x;
    int rbeg = bbase[bkt], rend = bbase[bkt + 1];
    if (t < 128) hist[t] = 0;
    __syncthreads();
    for (int j = rbeg + t; j < rend; j += 256)
        atomicAdd(&hist[data[j] & 127], 1);
    __syncthreads();
    if (t < 128) pfx[t] = hist[t];
    __syncthreads();
    for (int off = 1; off < 128; off <<= 1) {
        int u = (t < 128 && t >= off) ? pfx[t - off] : 0;
        __syncthreads();
        if (t < 128) pfx[t] += u;
        __syncthreads();
    }
    int nodeCount = min(128, NN - bkt * 128);
    if (t < nodeCount) {
        int excl = rbeg + pfx[t] - hist[t];
        csr_off[bkt * 128 + t] = excl;
        csr_cnt[bkt * 128 + t] = hist[t];
        curs[t] = excl;
        dinv[bkt * 128 + t] = rsqrtf((float)(hist[t] + 1));
    }
    __syncthreads();
    for (int j = rbeg + t; j < rend; j += 256) {
        uint32 r = data[j];
        int p = atomicAdd(&curs[r & 127], 1);
        csr_src[p] = (int)(r >> 7);
    }
}

// ---------------- fused layer 1: Agg(x) + matvec + tanh + fp16 pack -------------
__global__ void __launch_bounds__(256) k_aggmm1(const uint32* __restrict__ data,
                                                const int* __restrict__ bbase,
                                                const float* __restrict__ x,
                                                const float* __restrict__ dinv,
                                                const float* __restrict__ W1,
                                                const float* __restrict__ b1,
                                                uint32* __restrict__ Yp) {
    __shared__ float acc[128][4];
    __shared__ float w1s[4][128];
    __shared__ float b1s[128];
    int bkt = blockIdx.x;
    int t = threadIdx.x;
    if (t < 128) {
        acc[t][0] = 0.f; acc[t][1] = 0.f; acc[t][2] = 0.f; acc[t][3] = 0.f;
        b1s[t] = b1[t];
    }
    ((float*)w1s)[t] = W1[t];
    ((float*)w1s)[256 + t] = W1[256 + t];
    int rbeg = bbase[bkt], rend = bbase[bkt + 1];
    __syncthreads();
    for (int j = rbeg + t; j < rend; j += 256) {
        uint32 r = data[j];
        int s = (int)(r >> 7), dl = (int)(r & 127);
        float w = dinv[s];
        const float4 xv = *(const float4*)(x + (size_t)s * INF);
        atomicAdd(&acc[dl][0], xv.x * w);
        atomicAdd(&acc[dl][1], xv.y * w);
        atomicAdd(&acc[dl][2], xv.z * w);
        atomicAdd(&acc[dl][3], xv.w * w);
    }
    __syncthreads();
    int nbase = bkt * 128;
    #pragma unroll
    for (int rep = 0; rep < 32; ++rep) {
        int flat = rep * 256 + t;       // 8192 = 128 nodes * 64 uint outputs
        int node = flat >> 6;
        int fp = flat & 63;
        int gi = nbase + node;
        if (gi < NN) {
            float di = dinv[gi];
            const float4 xi = *(const float4*)(x + (size_t)gi * INF);
            float a0 = (acc[node][0] + xi.x * di) * di;
            float a1 = (acc[node][1] + xi.y * di) * di;
            float a2 = (acc[node][2] + xi.z * di) * di;
            float a3 = (acc[node][3] + xi.w * di) * di;
            int f0 = fp * 2;
            float d0 = b1s[f0]     + a0 * w1s[0][f0]     + a1 * w1s[1][f0]
                                   + a2 * w1s[2][f0]     + a3 * w1s[3][f0];
            float d1 = b1s[f0 + 1] + a0 * w1s[0][f0 + 1] + a1 * w1s[1][f0 + 1]
                                   + a2 * w1s[2][f0 + 1] + a3 * w1s[3][f0 + 1];
            Yp[(size_t)gi * 64 + fp] = pack_f16(tanhf(d0) * di, tanhf(d1) * di);
        }
    }
}

// ---------------- layer 2 gather: Zp = f16( dinv[i]*(sum Yp[s] + Yp[i]) ) -------
// fp16 rows, packed-half accumulate: 1 v_pk_add_f16 per uint (4x less VALU than
// the bf16 unpack path). Cross-lane reduce in f32 (once per node).
__global__ void k_aggy(const uint32* __restrict__ Yp, const int* __restrict__ csr_off,
                       const int* __restrict__ csr_cnt, const int* __restrict__ csr_src,
                       const float* __restrict__ dinv, uint32* __restrict__ Zp) {
    int wid = threadIdx.x >> 6;
    int lane = threadIdx.x & 63;
    int i = blockIdx.x * 4 + wid;
    if (i >= NN) return;
    int b = csr_off[i];
    int n = csr_cnt[i];
    int eg = lane >> 4, seg = lane & 15;

    __half2 h0 = bc_h2(0u), h1 = bc_h2(0u), h2 = bc_h2(0u), h3 = bc_h2(0u);
    int j = 0;
    for (; j + 8 <= n; j += 8) {       // all lanes valid: j+4+eg <= j+7 <= n-1
        int s0 = csr_src[b + j + eg];
        int s1 = csr_src[b + j + 4 + eg];
        uint4 v0 = *(const uint4*)(Yp + (size_t)s0 * 64 + seg * 4);
        uint4 v1 = *(const uint4*)(Yp + (size_t)s1 * 64 + seg * 4);
        h0 = __hadd2(h0, bc_h2(v0.x)); h1 = __hadd2(h1, bc_h2(v0.y));
        h2 = __hadd2(h2, bc_h2(v0.z)); h3 = __hadd2(h3, bc_h2(v0.w));
        h0 = __hadd2(h0, bc_h2(v1.x)); h1 = __hadd2(h1, bc_h2(v1.y));
        h2 = __hadd2(h2, bc_h2(v1.z)); h3 = __hadd2(h3, bc_h2(v1.w));
    }
    for (; j < n; j += 4) {
        int jj = j + eg;
        bool valid = jj < n;
        int s = valid ? csr_src[b + jj] : i;   // safe address; contribution masked
        uint4 v = *(const uint4*)(Yp + (size_t)s * 64 + seg * 4);
        if (valid) {
            h0 = __hadd2(h0, bc_h2(v.x)); h1 = __hadd2(h1, bc_h2(v.y));
            h2 = __hadd2(h2, bc_h2(v.z)); h3 = __hadd2(h3, bc_h2(v.w));
        }
    }
    // self-loop (once)
    {
        uint4 v = *(const uint4*)(Yp + (size_t)i * 64 + seg * 4);
        if (eg == 0) {
            h0 = __hadd2(h0, bc_h2(v.x)); h1 = __hadd2(h1, bc_h2(v.y));
            h2 = __hadd2(h2, bc_h2(v.z)); h3 = __hadd2(h3, bc_h2(v.w));
        }
    }
    // unpack to f32, reduce across the 4 edge-groups (butterfly)
    float a[8];
    { float2 f = __half22float2(h0); a[0] = f.x; a[1] = f.y; }
    { float2 f = __half22float2(h1); a[2] = f.x; a[3] = f.y; }
    { float2 f = __half22float2(h2); a[4] = f.x; a[5] = f.y; }
    { float2 f = __half22float2(h3); a[6] = f.x; a[7] = f.y; }
    #pragma unroll
    for (int m = 0; m < 8; ++m) {
        a[m] += __shfl_xor(a[m], 16, 64);
        a[m] += __shfl_xor(a[m], 32, 64);
    }
    if (eg == 0) {
        float di = dinv[i];
        uint4 o;
        o.x = pack_f16(a[0] * di, a[1] * di);
        o.y = pack_f16(a[2] * di, a[3] * di);
        o.z = pack_f16(a[4] * di, a[5] * di);
        o.w = pack_f16(a[6] * di, a[7] * di);
        *(uint4*)(Zp + (size_t)i * 64 + seg * 4) = o;
    }
}

// ---------------- O = tanh(Zp @ W2 + b2) via f16 MFMA, fused mean-pool ----------
__global__ void __launch_bounds__(256) k_mm2pool(
    const uint32* __restrict__ Zp, const float* __restrict__ W2,
    const float* __restrict__ b2, float* __restrict__ pooled) {
    int tid = threadIdx.x;
    int wid = tid >> 6, lane = tid & 63;
    int nsub = lane & 15;     // M (node) / N (feat) index within 16
    int kg = lane >> 4;       // k-group
    int fbase = wid * 32;

    // load W2 slice into registers, hi/lo fp16 split (22-bit combined mantissa)
    short8 Bh[2][4], Bl[2][4];
    #pragma unroll
    for (int c = 0; c < 2; ++c) {
        #pragma unroll
        for (int ks = 0; ks < 4; ++ks) {
            short8 h, l;
            #pragma unroll
            for (int i = 0; i < 8; ++i) {
                float w = W2[(size_t)(ks * 32 + kg * 8 + i) * H + (fbase + c * 16 + nsub)];
                __half hh = __float2half(w);
                float wl = w - __half2float(hh);
                __half hl = __float2half(wl);
                h[i] = (short)__half_as_ushort(hh);
                l[i] = (short)__half_as_ushort(hl);
            }
            Bh[c][ks] = h;
            Bl[c][ks] = l;
        }
    }
    float bb0 = b2[fbase + nsub];
    float bb1 = b2[fbase + 16 + nsub];
    float pool0 = 0.f, pool1 = 0.f;

    const int ntiles = NN / 16;          // 6250 exact
    const int stride = (int)gridDim.x;
    int t = (int)blockIdx.x;

    short8 A[4];
    if (t < ntiles) {
        const uint32* rp = Zp + (size_t)(t * 16 + nsub) * 64 + kg * 4;
        #pragma unroll
        for (int ks = 0; ks < 4; ++ks) A[ks] = *(const short8*)(rp + ks * 16);
    }
    while (t < ntiles) {
        int tn = t + stride;
        short8 An[4];
        if (tn < ntiles) {
            const uint32* rp = Zp + (size_t)(tn * 16 + nsub) * 64 + kg * 4;
            #pragma unroll
            for (int ks = 0; ks < 4; ++ks) An[ks] = *(const short8*)(rp + ks * 16);
        }
        {
            f32x4 acch0 = {0.f,0.f,0.f,0.f}, accl0 = {0.f,0.f,0.f,0.f};
            f32x4 acch1 = {0.f,0.f,0.f,0.f}, accl1 = {0.f,0.f,0.f,0.f};
            #pragma unroll
            for (int ks = 0; ks < 4; ++ks) {
                acch0 = __builtin_amdgcn_mfma_f32_16x16x32_f16(A[ks], Bh[0][ks], acch0, 0, 0, 0);
                accl0 = __builtin_amdgcn_mfma_f32_16x16x32_f16(A[ks], Bl[0][ks], accl0, 0, 0, 0);
                acch1 = __builtin_amdgcn_mfma_f32_16x16x32_f16(A[ks], Bh[1][ks], acch1, 0, 0, 0);
                accl1 = __builtin_amdgcn_mfma_f32_16x16x32_f16(A[ks], Bl[1][ks], accl1, 0, 0, 0);
            }
            #pragma unroll
            for (int r = 0; r < 4; ++r) {
                pool0 += tanhf(acch0[r] + accl0[r] + bb0);
                pool1 += tanhf(acch1[r] + accl1[r] + bb1);
            }
        }
        #pragma unroll
        for (int ks = 0; ks < 4; ++ks) A[ks] = An[ks];
        t = tn;
    }

    // reduce over the 4 kg-duplicated lanes (rows already summed into pool regs)
    pool0 += __shfl_xor(pool0, 16, 64);
    pool0 += __shfl_xor(pool0, 32, 64);
    pool1 += __shfl_xor(pool1, 16, 64);
    pool1 += __shfl_xor(pool1, 32, 64);
    if (kg == 0) {
        atomicAdd(&pooled[fbase + nsub], pool0);
        atomicAdd(&pooled[fbase + 16 + nsub], pool1);
    }
}

// ---------------- final: vel = (pooled/N) @ Wfc + bfc, mask by in_size ----------
__global__ void k_final(const float* __restrict__ pooled, const float* __restrict__ Wfc,
                        const float* __restrict__ bfc, const int* __restrict__ in_size,
                        float* __restrict__ out) {
    int t = threadIdx.x;
    if (t >= RR * OUTF) return;
    const float invn = 1.0f / (float)NN;
    float a = bfc[t];
    for (int k = 0; k < H; ++k) a += (pooled[k] * invn) * Wfc[k * (RR * OUTF) + t];
    int r = t >> 1;
    out[t] = (r < *in_size) ? a : 0.f;
}

extern "C" void kernel_launch(void* const* d_in, const int* in_sizes, int n_in,
                              void* d_out, int out_size, void* d_ws, size_t ws_size,
                              hipStream_t stream) {
    const float* x   = (const float*)d_in[0];
    const int*   ei  = (const int*)d_in[1];     // [2, E]
    const float* W1  = (const float*)d_in[3];
    const float* b1  = (const float*)d_in[4];
    const float* W2  = (const float*)d_in[5];
    const float* b2  = (const float*)d_in[6];
    const float* Wfc = (const float*)d_in[7];
    const float* bfc = (const float*)d_in[8];
    float* out = (float*)d_out;

    const int* srcp = ei;
    const int* dstp = ei + NE;

    // workspace layout (512B aligned chunks)
    char* ws = (char*)d_ws;
    size_t off = 0;
    auto alloc = [&](size_t bytes) { void* p = ws + off; off += (bytes + 511) & ~(size_t)511; return p; };
    int*    histG   = (int*)alloc((size_t)NBLK * NBP * 4);    // 307 KB
    int*    offs    = (int*)alloc((size_t)NBLK * NBP * 4);    // 307 KB
    int*    btot    = (int*)alloc((size_t)NB * 4);
    int*    bbase   = (int*)alloc(((size_t)NB + 1) * 4);
    uint32* data    = (uint32*)alloc((size_t)NE * 4);         // 6.4 MB exact
    float*  dinv    = (float*)alloc((size_t)NN * 4);
    int*    csr_off = (int*)alloc((size_t)NN * 4);
    int*    csr_cnt = (int*)alloc((size_t)NN * 4);
    int*    csr_src = (int*)alloc((size_t)NE * 4);            // 6.4 MB
    uint32* Yp      = (uint32*)alloc((size_t)NN * 64 * 4);    // packed fp16, premult dinv
    uint32* Zp      = (uint32*)alloc((size_t)NN * 64 * 4);    // packed fp16 layer-2 agg
    float*  pooled  = (float*)alloc(H * 4);
    int*    in_size = (int*)alloc(64);
    (void)off; (void)ws_size; (void)in_sizes; (void)n_in; (void)out_size;

    const int nbN = (NN + 255) / 256;        // 391
    const int nbW = (NN + 3) / 4;            // 4 waves (nodes) per block

    k_init_small<<<1, 256, 0, stream>>>(pooled, in_size);
    k_init_nodes<<<nbN, 256, 0, stream>>>(x, in_size);
    k_hist<<<NBLK, 256, 0, stream>>>(dstp, histG);
    k_btotoffs<<<(NB + 255) / 256, 256, 0, stream>>>(histG, offs, btot);
    k_bbase<<<1, 1024, 0, stream>>>(btot, bbase);
    k_scat2<<<NBLK, 256, 0, stream>>>(srcp, dstp, offs, bbase, data);
    k_build<<<NB, 256, 0, stream>>>(data, bbase, csr_off, csr_cnt, csr_src, dinv);
    k_aggmm1<<<NB, 256, 0, stream>>>(data, bbase, x, dinv, W1, b1, Yp);
    k_aggy<<<nbW, 256, 0, stream>>>(Yp, csr_off, csr_cnt, csr_src, dinv, Zp);
    k_mm2pool<<<512, 256, 0, stream>>>(Zp, W2, b2, pooled);
    k_final<<<1, 64, 0, stream>>>(pooled, Wfc, bfc, in_size, out);
}

// Round 12
// 316.026 us; speedup vs baseline: 1.5939x; 1.0105x over previous
//
#include <hip/hip_runtime.h>
#include <hip/hip_fp16.h>

#define NN 100000
#define NE 1600000
#define INF 4
#define H 128
#define RR 20
#define OUTF 2
#define NB 782            // buckets of 128 nodes: ceil(100000/128)
#define NBP 784           // padded row stride for hist/offs matrices
#define EPB 16384         // edges per partition block
#define NBLK ((NE + EPB - 1) / EPB)   // 98
#define ASPLIT 4          // sub-blocks per bucket in layer-1 aggregation

typedef unsigned int uint32;
typedef __attribute__((ext_vector_type(8))) short short8;   // 8 f16 (4 VGPR) MFMA A/B frag
typedef __attribute__((ext_vector_type(4))) float f32x4;    // MFMA C/D frag

// pack two floats to fp16 pair (RNE): x -> low 16, y -> high 16
__device__ inline uint32 pack_f16(float x, float y) {
    return (uint32)__half_as_ushort(__float2half(x)) |
           ((uint32)__half_as_ushort(__float2half(y)) << 16);
}
__device__ inline __half2 bc_h2(uint32 u) {
    union { uint32 u; __half2 h; } c; c.u = u; return c.h;
}

// ---------------- init ----------------
__global__ void k_init_small(float* __restrict__ pooled, int* __restrict__ in_size) {
    int t = threadIdx.x;
    if (t < H) pooled[t] = 0.f;
    if (t == H) *in_size = 0;
}

__global__ void k_init_nodes(const float* __restrict__ x, int* __restrict__ in_size) {
    int i = blockIdx.x * 256 + threadIdx.x;
    bool pred = false;
    if (i < NN) {
        float x0 = x[(size_t)i * INF + 0];
        float x1 = x[(size_t)i * INF + 1];
        pred = (x0 != 0.f) && (x1 != 0.f);
    }
    unsigned long long m = __ballot(pred);
    if ((threadIdx.x & 63) == 0) {
        int c = __popcll(m);
        if (c) atomicAdd(in_size, c);
    }
}

// ---------------- counting-sort partition (LDS atomics only) --------------------
__global__ void __launch_bounds__(256) k_hist(const int* __restrict__ dst,
                                              int* __restrict__ histG) {
    __shared__ int h[NB];
    int b = blockIdx.x, t = threadIdx.x;
    for (int i = t; i < NB; i += 256) h[i] = 0;
    __syncthreads();
    int e0 = b * EPB, eend = min(e0 + EPB, NE);
    for (int e = e0 + t; e < eend; e += 256) atomicAdd(&h[dst[e] >> 7], 1);
    __syncthreads();
    for (int i = t; i < NB; i += 256) histG[b * NBP + i] = h[i];
}

__global__ void k_btotoffs(const int* __restrict__ histG, int* __restrict__ offs,
                           int* __restrict__ btot) {
    int bkt = blockIdx.x * 256 + threadIdx.x;
    if (bkt >= NB) return;
    int run = 0;
    for (int j = 0; j < NBLK; ++j) {
        int v = histG[j * NBP + bkt];
        offs[j * NBP + bkt] = run;
        run += v;
    }
    btot[bkt] = run;
}

__global__ void __launch_bounds__(1024) k_bbase(const int* __restrict__ btot,
                                                int* __restrict__ bbase) {
    __shared__ int sm[1024];
    int t = threadIdx.x;
    int v = (t < NB) ? btot[t] : 0;
    sm[t] = v;
    __syncthreads();
    for (int off = 1; off < 1024; off <<= 1) {
        int u = (t >= off) ? sm[t - off] : 0;
        __syncthreads();
        sm[t] += u;
        __syncthreads();
    }
    if (t < NB) bbase[t] = sm[t] - v;
    if (t == 0) bbase[NB] = NE;
}

__global__ void __launch_bounds__(256) k_scat2(const int* __restrict__ src,
                                               const int* __restrict__ dst,
                                               const int* __restrict__ offs,
                                               const int* __restrict__ bbase,
                                               uint32* __restrict__ data) {
    __shared__ int cur[NB];
    int b = blockIdx.x, t = threadIdx.x;
    for (int i = t; i < NB; i += 256) cur[i] = offs[b * NBP + i] + bbase[i];
    __syncthreads();
    int e0 = b * EPB, eend = min(e0 + EPB, NE);
    for (int e = e0 + t; e < eend; e += 256) {
        int s = src[e], d = dst[e];
        int p = atomicAdd(&cur[d >> 7], 1);
        data[p] = ((uint32)s << 7) | (uint32)(d & 127);
    }
}

// one block per bucket: histogram -> csr_off/csr_cnt/dinv/xd + node-sorted csr_src.
__global__ void __launch_bounds__(256) k_build(const uint32* __restrict__ data,
                                               const int* __restrict__ bbase,
                                               const float* __restrict__ x,
                                               int* __restrict__ csr_off,
                                               int* __restrict__ csr_cnt,
                                               int* __restrict__ csr_src,
                                               float* __restrict__ dinv,
                                               float4* __restrict__ xd) {
    __shared__ int hist[128], pfx[128], curs[128];
    int bkt = blockIdx.x;
    int t = threadIdx.x;
    int rbeg = bbase[bkt], rend = bbase[bkt + 1];
    if (t < 128) hist[t] = 0;
    __syncthreads();
    for (int j = rbeg + t; j < rend; j += 256)
        atomicAdd(&hist[data[j] & 127], 1);
    __syncthreads();
    if (t < 128) pfx[t] = hist[t];
    __syncthreads();
    for (int off = 1; off < 128; off <<= 1) {
        int u = (t < 128 && t >= off) ? pfx[t - off] : 0;
        __syncthreads();
        if (t < 128) pfx[t] += u;
        __syncthreads();
    }
    int nodeCount = min(128, NN - bkt * 128);
    if (t < nodeCount) {
        int gi = bkt * 128 + t;
        int excl = rbeg + pfx[t] - hist[t];
        csr_off[gi] = excl;
        csr_cnt[gi] = hist[t];
        curs[t] = excl;
        float di = rsqrtf((float)(hist[t] + 1));
        dinv[gi] = di;
        const float4 xv = *(const float4*)(x + (size_t)gi * INF);
        xd[gi] = make_float4(xv.x * di, xv.y * di, xv.z * di, xv.w * di);
    }
    __syncthreads();
    for (int j = rbeg + t; j < rend; j += 256) {
        uint32 r = data[j];
        int p = atomicAdd(&curs[r & 127], 1);
        csr_src[p] = (int)(r >> 7);
    }
}

// ---------------- layer-1 aggregation: 4 blocks per bucket, no atomics ----------
// Block (bkt, sp) accumulates its quarter of the bucket's records into LDS
// acc[128][4] (one float4 gather of L2-resident xd per edge), then writes its
// PRIVATE part slice coalesced. Grid 3128 -> full occupancy.
__global__ void __launch_bounds__(256) k_aggx4(const uint32* __restrict__ data,
                                               const int* __restrict__ bbase,
                                               const float4* __restrict__ xd,
                                               float* __restrict__ Axpart) {
    __shared__ float acc[128][4];
    int bkt = blockIdx.x >> 2, sp = blockIdx.x & 3;
    int t = threadIdx.x;
    if (t < 128) { acc[t][0] = 0.f; acc[t][1] = 0.f; acc[t][2] = 0.f; acc[t][3] = 0.f; }
    int rbeg = bbase[bkt], rend = bbase[bkt + 1];
    int len = rend - rbeg;
    int q0 = rbeg + ((long long)len * sp >> 2);
    int q1 = rbeg + ((long long)len * (sp + 1) >> 2);
    __syncthreads();
    for (int j = q0 + t; j < q1; j += 256) {
        uint32 r = data[j];
        int s = (int)(r >> 7), dl = (int)(r & 127);
        const float4 v = xd[s];
        atomicAdd(&acc[dl][0], v.x);
        atomicAdd(&acc[dl][1], v.y);
        atomicAdd(&acc[dl][2], v.z);
        atomicAdd(&acc[dl][3], v.w);
    }
    __syncthreads();
    float* dstp = Axpart + (size_t)blockIdx.x * 512;
    for (int i = t; i < 512; i += 256) dstp[i] = ((const float*)acc)[i];
}

// merge 4 parts + self-term, scale by dinv -> Ax  (all loads/stores coalesced)
__global__ void k_merge(const float* __restrict__ Axpart, const float4* __restrict__ xd,
                        const float* __restrict__ dinv, float4* __restrict__ Ax) {
    int i = blockIdx.x * 256 + threadIdx.x;
    if (i >= NN) return;
    int bkt = i >> 7, nl = i & 127;
    float4 a = xd[i];   // self-loop term
    #pragma unroll
    for (int sp = 0; sp < 4; ++sp) {
        const float4 p = *(const float4*)(Axpart + ((size_t)(bkt * 4 + sp)) * 512 + nl * 4);
        a.x += p.x; a.y += p.y; a.z += p.z; a.w += p.w;
    }
    float di = dinv[i];
    Ax[i] = make_float4(a.x * di, a.y * di, a.z * di, a.w * di);
}

// matvec + tanh + fp16 pack: Yp = pack(tanh(Ax@W1+b1)*dinv), wave per node
__global__ void __launch_bounds__(256) k_mm1b(const float4* __restrict__ Ax,
                                              const float* __restrict__ dinv,
                                              const float* __restrict__ W1,
                                              const float* __restrict__ b1,
                                              uint32* __restrict__ Yp) {
    __shared__ float w1s[4][128];
    __shared__ float b1s[128];
    int t = threadIdx.x;
    if (t < 128) b1s[t] = b1[t];
    ((float*)w1s)[t] = W1[t];
    ((float*)w1s)[256 + t] = W1[256 + t];
    __syncthreads();
    int wid = t >> 6, lane = t & 63;
    int node = blockIdx.x * 4 + wid;
    if (node >= NN) return;
    const float4 a = Ax[node];
    float di = dinv[node];
    int f0 = lane * 2;
    float d0 = b1s[f0]     + a.x * w1s[0][f0]     + a.y * w1s[1][f0]
                           + a.z * w1s[2][f0]     + a.w * w1s[3][f0];
    float d1 = b1s[f0 + 1] + a.x * w1s[0][f0 + 1] + a.y * w1s[1][f0 + 1]
                           + a.z * w1s[2][f0 + 1] + a.w * w1s[3][f0 + 1];
    Yp[(size_t)node * 64 + lane] = pack_f16(tanhf(d0) * di, tanhf(d1) * di);
}

// ---------------- layer 2 gather: Zp = f16( dinv[i]*(sum Yp[s] + Yp[i]) ) -------
__global__ void k_aggy(const uint32* __restrict__ Yp, const int* __restrict__ csr_off,
                       const int* __restrict__ csr_cnt, const int* __restrict__ csr_src,
                       const float* __restrict__ dinv, uint32* __restrict__ Zp) {
    int wid = threadIdx.x >> 6;
    int lane = threadIdx.x & 63;
    int i = blockIdx.x * 4 + wid;
    if (i >= NN) return;
    int b = csr_off[i];
    int n = csr_cnt[i];
    int eg = lane >> 4, seg = lane & 15;

    __half2 h0 = bc_h2(0u), h1 = bc_h2(0u), h2 = bc_h2(0u), h3 = bc_h2(0u);
    int j = 0;
    for (; j + 8 <= n; j += 8) {       // all lanes valid: j+4+eg <= j+7 <= n-1
        int s0 = csr_src[b + j + eg];
        int s1 = csr_src[b + j + 4 + eg];
        uint4 v0 = *(const uint4*)(Yp + (size_t)s0 * 64 + seg * 4);
        uint4 v1 = *(const uint4*)(Yp + (size_t)s1 * 64 + seg * 4);
        h0 = __hadd2(h0, bc_h2(v0.x)); h1 = __hadd2(h1, bc_h2(v0.y));
        h2 = __hadd2(h2, bc_h2(v0.z)); h3 = __hadd2(h3, bc_h2(v0.w));
        h0 = __hadd2(h0, bc_h2(v1.x)); h1 = __hadd2(h1, bc_h2(v1.y));
        h2 = __hadd2(h2, bc_h2(v1.z)); h3 = __hadd2(h3, bc_h2(v1.w));
    }
    for (; j < n; j += 4) {
        int jj = j + eg;
        bool valid = jj < n;
        int s = valid ? csr_src[b + jj] : i;   // safe address; contribution masked
        uint4 v = *(const uint4*)(Yp + (size_t)s * 64 + seg * 4);
        if (valid) {
            h0 = __hadd2(h0, bc_h2(v.x)); h1 = __hadd2(h1, bc_h2(v.y));
            h2 = __hadd2(h2, bc_h2(v.z)); h3 = __hadd2(h3, bc_h2(v.w));
        }
    }
    // self-loop (once)
    {
        uint4 v = *(const uint4*)(Yp + (size_t)i * 64 + seg * 4);
        if (eg == 0) {
            h0 = __hadd2(h0, bc_h2(v.x)); h1 = __hadd2(h1, bc_h2(v.y));
            h2 = __hadd2(h2, bc_h2(v.z)); h3 = __hadd2(h3, bc_h2(v.w));
        }
    }
    // unpack to f32, reduce across the 4 edge-groups (butterfly)
    float a[8];
    { float2 f = __half22float2(h0); a[0] = f.x; a[1] = f.y; }
    { float2 f = __half22float2(h1); a[2] = f.x; a[3] = f.y; }
    { float2 f = __half22float2(h2); a[4] = f.x; a[5] = f.y; }
    { float2 f = __half22float2(h3); a[6] = f.x; a[7] = f.y; }
    #pragma unroll
    for (int m = 0; m < 8; ++m) {
        a[m] += __shfl_xor(a[m], 16, 64);
        a[m] += __shfl_xor(a[m], 32, 64);
    }
    if (eg == 0) {
        float di = dinv[i];
        uint4 o;
        o.x = pack_f16(a[0] * di, a[1] * di);
        o.y = pack_f16(a[2] * di, a[3] * di);
        o.z = pack_f16(a[4] * di, a[5] * di);
        o.w = pack_f16(a[6] * di, a[7] * di);
        *(uint4*)(Zp + (size_t)i * 64 + seg * 4) = o;
    }
}

// ---------------- O = tanh(Zp @ W2 + b2) via f16 MFMA, fused mean-pool ----------
__global__ void __launch_bounds__(256) k_mm2pool(
    const uint32* __restrict__ Zp, const float* __restrict__ W2,
    const float* __restrict__ b2, float* __restrict__ pooled) {
    int tid = threadIdx.x;
    int wid = tid >> 6, lane = tid & 63;
    int nsub = lane & 15;     // M (node) / N (feat) index within 16
    int kg = lane >> 4;       // k-group
    int fbase = wid * 32;

    // load W2 slice into registers, hi/lo fp16 split (22-bit combined mantissa)
    short8 Bh[2][4], Bl[2][4];
    #pragma unroll
    for (int c = 0; c < 2; ++c) {
        #pragma unroll
        for (int ks = 0; ks < 4; ++ks) {
            short8 h, l;
            #pragma unroll
            for (int i = 0; i < 8; ++i) {
                float w = W2[(size_t)(ks * 32 + kg * 8 + i) * H + (fbase + c * 16 + nsub)];
                __half hh = __float2half(w);
                float wl = w - __half2float(hh);
                __half hl = __float2half(wl);
                h[i] = (short)__half_as_ushort(hh);
                l[i] = (short)__half_as_ushort(hl);
            }
            Bh[c][ks] = h;
            Bl[c][ks] = l;
        }
    }
    float bb0 = b2[fbase + nsub];
    float bb1 = b2[fbase + 16 + nsub];
    float pool0 = 0.f, pool1 = 0.f;

    const int ntiles = NN / 16;          // 6250 exact
    const int stride = (int)gridDim.x;
    int t = (int)blockIdx.x;

    short8 A[4];
    if (t < ntiles) {
        const uint32* rp = Zp + (size_t)(t * 16 + nsub) * 64 + kg * 4;
        #pragma unroll
        for (int ks = 0; ks < 4; ++ks) A[ks] = *(const short8*)(rp + ks * 16);
    }
    while (t < ntiles) {
        int tn = t + stride;
        short8 An[4];
        if (tn < ntiles) {
            const uint32* rp = Zp + (size_t)(tn * 16 + nsub) * 64 + kg * 4;
            #pragma unroll
            for (int ks = 0; ks < 4; ++ks) An[ks] = *(const short8*)(rp + ks * 16);
        }
        {
            f32x4 acch0 = {0.f,0.f,0.f,0.f}, accl0 = {0.f,0.f,0.f,0.f};
            f32x4 acch1 = {0.f,0.f,0.f,0.f}, accl1 = {0.f,0.f,0.f,0.f};
            #pragma unroll
            for (int ks = 0; ks < 4; ++ks) {
                acch0 = __builtin_amdgcn_mfma_f32_16x16x32_f16(A[ks], Bh[0][ks], acch0, 0, 0, 0);
                accl0 = __builtin_amdgcn_mfma_f32_16x16x32_f16(A[ks], Bl[0][ks], accl0, 0, 0, 0);
                acch1 = __builtin_amdgcn_mfma_f32_16x16x32_f16(A[ks], Bh[1][ks], acch1, 0, 0, 0);
                accl1 = __builtin_amdgcn_mfma_f32_16x16x32_f16(A[ks], Bl[1][ks], accl1, 0, 0, 0);
            }
            #pragma unroll
            for (int r = 0; r < 4; ++r) {
                pool0 += tanhf(acch0[r] + accl0[r] + bb0);
                pool1 += tanhf(acch1[r] + accl1[r] + bb1);
            }
        }
        #pragma unroll
        for (int ks = 0; ks < 4; ++ks) A[ks] = An[ks];
        t = tn;
    }

    // reduce over the 4 kg-duplicated lanes (rows already summed into pool regs)
    pool0 += __shfl_xor(pool0, 16, 64);
    pool0 += __shfl_xor(pool0, 32, 64);
    pool1 += __shfl_xor(pool1, 16, 64);
    pool1 += __shfl_xor(pool1, 32, 64);
    if (kg == 0) {
        atomicAdd(&pooled[fbase + nsub], pool0);
        atomicAdd(&pooled[fbase + 16 + nsub], pool1);
    }
}

// ---------------- final: vel = (pooled/N) @ Wfc + bfc, mask by in_size ----------
__global__ void k_final(const float* __restrict__ pooled, const float* __restrict__ Wfc,
                        const float* __restrict__ bfc, const int* __restrict__ in_size,
                        float* __restrict__ out) {
    int t = threadIdx.x;
    if (t >= RR * OUTF) return;
    const float invn = 1.0f / (float)NN;
    float a = bfc[t];
    for (int k = 0; k < H; ++k) a += (pooled[k] * invn) * Wfc[k * (RR * OUTF) + t];
    int r = t >> 1;
    out[t] = (r < *in_size) ? a : 0.f;
}

extern "C" void kernel_launch(void* const* d_in, const int* in_sizes, int n_in,
                              void* d_out, int out_size, void* d_ws, size_t ws_size,
                              hipStream_t stream) {
    const float* x   = (const float*)d_in[0];
    const int*   ei  = (const int*)d_in[1];     // [2, E]
    const float* W1  = (const float*)d_in[3];
    const float* b1  = (const float*)d_in[4];
    const float* W2  = (const float*)d_in[5];
    const float* b2  = (const float*)d_in[6];
    const float* Wfc = (const float*)d_in[7];
    const float* bfc = (const float*)d_in[8];
    float* out = (float*)d_out;

    const int* srcp = ei;
    const int* dstp = ei + NE;

    // workspace layout (512B aligned chunks)
    char* ws = (char*)d_ws;
    size_t off = 0;
    auto alloc = [&](size_t bytes) { void* p = ws + off; off += (bytes + 511) & ~(size_t)511; return p; };
    int*    histG   = (int*)alloc((size_t)NBLK * NBP * 4);    // 307 KB
    int*    offs    = (int*)alloc((size_t)NBLK * NBP * 4);    // 307 KB
    int*    btot    = (int*)alloc((size_t)NB * 4);
    int*    bbase   = (int*)alloc(((size_t)NB + 1) * 4);
    uint32* data    = (uint32*)alloc((size_t)NE * 4);         // 6.4 MB exact
    float*  dinv    = (float*)alloc((size_t)NN * 4);
    float4* xd      = (float4*)alloc((size_t)NN * 16);        // x*dinv, L2-resident
    int*    csr_off = (int*)alloc((size_t)NN * 4);
    int*    csr_cnt = (int*)alloc((size_t)NN * 4);
    int*    csr_src = (int*)alloc((size_t)NE * 4);            // 6.4 MB
    float*  Axpart  = (float*)alloc((size_t)NB * ASPLIT * 512 * 4);   // 6.4 MB
    float4* Ax      = (float4*)alloc((size_t)NN * 16);
    uint32* Yp      = (uint32*)alloc((size_t)NN * 64 * 4);    // packed fp16, premult dinv
    uint32* Zp      = (uint32*)alloc((size_t)NN * 64 * 4);    // packed fp16 layer-2 agg
    float*  pooled  = (float*)alloc(H * 4);
    int*    in_size = (int*)alloc(64);
    (void)off; (void)ws_size; (void)in_sizes; (void)n_in; (void)out_size;

    const int nbN = (NN + 255) / 256;        // 391
    const int nbW = (NN + 3) / 4;            // 4 waves (nodes) per block

    k_init_small<<<1, 256, 0, stream>>>(pooled, in_size);
    k_init_nodes<<<nbN, 256, 0, stream>>>(x, in_size);
    k_hist<<<NBLK, 256, 0, stream>>>(dstp, histG);
    k_btotoffs<<<(NB + 255) / 256, 256, 0, stream>>>(histG, offs, btot);
    k_bbase<<<1, 1024, 0, stream>>>(btot, bbase);
    k_scat2<<<NBLK, 256, 0, stream>>>(srcp, dstp, offs, bbase, data);
    k_build<<<NB, 256, 0, stream>>>(data, bbase, x, csr_off, csr_cnt, csr_src, dinv, xd);
    k_aggx4<<<NB * ASPLIT, 256, 0, stream>>>(data, bbase, xd, Axpart);
    k_merge<<<nbN, 256, 0, stream>>>(Axpart, xd, dinv, Ax);
    k_mm1b<<<nbW, 256, 0, stream>>>(Ax, dinv, W1, b1, Yp);
    k_aggy<<<nbW, 256, 0, stream>>>(Yp, csr_off, csr_cnt, csr_src, dinv, Zp);
    k_mm2pool<<<512, 256, 0, stream>>>(Zp, W2, b2, pooled);
    k_final<<<1, 64, 0, stream>>>(pooled, Wfc, bfc, in_size, out);
}